// Round 8
// baseline (1983.647 us; speedup 1.0000x reference)
//
#include <hip/hip_runtime.h>

typedef unsigned short u16;
typedef unsigned int u32;
typedef unsigned long long u64;
typedef short v8s __attribute__((ext_vector_type(8)));
typedef float v4f __attribute__((ext_vector_type(4)));

#define NN 4096
#define BATCH 32

__device__ __forceinline__ float b2f(u16 u) {
  union { u32 i; float f; } c; c.i = ((u32)u) << 16; return c.f;
}
__device__ __forceinline__ u16 f2b(float f) {
  union { float f; u32 i; } c; c.f = f;
  u32 x = c.i;
  return (u16)((x + 0x7fffu + ((x >> 16) & 1u)) >> 16);
}
__device__ __forceinline__ u32 pk2(float a, float b) {
  return (u32)f2b(a) | ((u32)f2b(b) << 16);
}

typedef const __attribute__((address_space(1))) u32* gp_t;
typedef __attribute__((address_space(3))) u32* lp_t;
__device__ __forceinline__ void gld16(const u16* g, u16* l) {
  __builtin_amdgcn_global_load_lds((gp_t)g, (lp_t)l, 16, 0, 0);
}

#define CBAR() asm volatile("" ::: "memory")
#define BARRIER() do { CBAR(); __builtin_amdgcn_s_barrier(); CBAR(); } while (0)
#define LGKM0() asm volatile("s_waitcnt lgkmcnt(0)" ::: "memory")
#define VMC6() asm volatile("s_waitcnt vmcnt(6)" ::: "memory")
#define VMC3() asm volatile("s_waitcnt vmcnt(3)" ::: "memory")
#define VMC0() asm volatile("s_waitcnt vmcnt(0)" ::: "memory")

// ---------------------------------------------------------------------------
// cvtS: f32 -> bf16 (RNE), 8 elems/thread. grid: 8192 x 256 for 16.8M elems.
// ---------------------------------------------------------------------------
__global__ __launch_bounds__(256) void cvtS(const float* __restrict__ S,
                                            u16* __restrict__ Sb) {
  const u64 idx = ((u64)blockIdx.x * 256 + threadIdx.x) * 8;
  const float4 a = *(const float4*)(S + idx);
  const float4 b = *(const float4*)(S + idx + 4);
  uint4 o;
  o.x = pk2(a.x, a.y); o.y = pk2(a.z, a.w);
  o.z = pk2(b.x, b.y); o.w = pk2(b.z, b.w);
  *(uint4*)(Sb + idx) = o;
}

// ---------------------------------------------------------------------------
// gemm256 (v8): faithful m201 8-phase port. 256x256 tile, BK=64, 8 waves
// (2Mx4N). Fragment-interleaved mapping: A-row = i*32+wm*16, B-row =
// j*64+wn*16, so A-h0/B-h0 die after ph1, B-h1 after ph2, A-h1 after ph3.
// Per phase: {ds_reads | 1 half-tile stage (2 gld) | barrier | lgkm0 |
// setprio + 16 MFMA + setprio | barrier}; vmcnt(6) ONLY at ph4/ph8
// (3 half-tiles in flight). 2 K-tiles per iteration. grid (16, C/256),
// block 512.
// ---------------------------------------------------------------------------
__global__ __launch_bounds__(512, 2) void gemm256(const u16* __restrict__ A,
                                                  const u16* __restrict__ B,
                                                  u16* __restrict__ Ct,
                                                  const u16* __restrict__ Xt) {
  // buf b at b*32768 u16: A-h0 +0 | A-h1 +8192 | B-h0 +16384 | B-h1 +24576
  __shared__ __align__(16) u16 lds[65536];
  const int t = threadIdx.x;
  const int wave = t >> 6, lane = t & 63;
  const int q = lane >> 4, r16 = lane & 15;
  const int wm = wave >> 2, wn = wave & 3;

  const int nwg = (int)(gridDim.x * gridDim.y);
  const int bid = (int)(blockIdx.y * gridDim.x + blockIdx.x);
  const int swz = (bid & 7) * (nwg >> 3) + (bid >> 3);
  const int m0 = (swz & 15) << 8;   // gridDim.x == 16 always
  const int c0 = (swz >> 4) << 8;

  v4f acc[8][4];
  const v4f vz = {0.f, 0.f, 0.f, 0.f};
#pragma unroll
  for (int i = 0; i < 8; ++i)
#pragma unroll
    for (int j = 0; j < 4; ++j) acc[i][j] = vz;

  // staging: thread t covers row (t>>3), 16B slot (t&7), source col
  // pre-swizzled by row&7 so swizzled ds_reads see linear data
  const int srow = t >> 3;
  const int sslot = ((t & 7) ^ (srow & 7)) << 3;
  const u16* pA = A + (u64)(m0 + srow) * NN + sslot;
  const u16* pB = B + (u64)(c0 + srow) * NN + sslot;
  const u64 rstep = (u64)64 * NN;
  const u64 hstep = (u64)128 * NN;
  u16* lw = lds + (wave << 9);

  // ds_read bases: A frag i at row i*32+wm*16+r16 -> + (i<<11);
  // B frag j at row j*64+wn*16+r16 -> + (j<<12). ksub1 via ^32.
  const int sw8 = (q ^ (r16 & 7)) << 3;
  const int aBase = (((wm << 4) + r16) << 6) + sw8;
  const int bBase = 16384 + (((wn << 4) + r16) << 6) + sw8;

  // prologue: 7 half-tiles in strict order; vmcnt(6) drains tile0 fully.
  gld16(pA, lw);  gld16(pA + rstep, lw + 4096);                             // Ah0(0)
  gld16(pB, lw + 16384);  gld16(pB + rstep, lw + 20480);                    // Bh0(0)
  gld16(pB + hstep, lw + 24576);  gld16(pB + hstep + rstep, lw + 28672);    // Bh1(0)
  gld16(pA + hstep, lw + 8192);  gld16(pA + hstep + rstep, lw + 12288);     // Ah1(0)
  gld16(pA + 64, lw + 32768);  gld16(pA + 64 + rstep, lw + 32768 + 4096);   // Ah0(1)
  gld16(pB + 64, lw + 32768 + 16384);  gld16(pB + 64 + rstep, lw + 32768 + 20480); // Bh0(1)
  gld16(pB + 64 + hstep, lw + 32768 + 24576);
  gld16(pB + 64 + hstep + rstep, lw + 32768 + 28672);                       // Bh1(1)
  VMC6();
  BARRIER();

  v8s af[4][2], bf01[2][2], bf23[2][2];

#pragma unroll 1
  for (int it = 0; it < 32; ++it) {
    const int T = it << 1;
    const u64 k1 = (u64)(T + 1) << 6;
    const u64 k2 = (u64)(T + 2 < 64 ? T + 2 : 63) << 6;
    const u64 k3 = (u64)(T + 3 < 64 ? T + 3 : 63) << 6;

    // ================= tile T (buf0) =================
    // ph1: read af03+bf01 | stage Ah1(T+1)->buf1 | Q(i0-3,j0-1)
#pragma unroll
    for (int i = 0; i < 4; ++i) {
      const int a = aBase + (i << 11);
      af[i][0] = *(const v8s*)(lds + a);
      af[i][1] = *(const v8s*)(lds + (a ^ 32));
    }
#pragma unroll
    for (int j = 0; j < 2; ++j) {
      const int b = bBase + (j << 12);
      bf01[j][0] = *(const v8s*)(lds + b);
      bf01[j][1] = *(const v8s*)(lds + (b ^ 32));
    }
    gld16(pA + hstep + k1, lw + 32768 + 8192);
    gld16(pA + hstep + rstep + k1, lw + 32768 + 12288);
    BARRIER(); LGKM0();
    __builtin_amdgcn_s_setprio(1);
#pragma unroll
    for (int i = 0; i < 4; ++i)
#pragma unroll
      for (int j = 0; j < 2; ++j) {
        acc[i][j] = __builtin_amdgcn_mfma_f32_16x16x32_bf16(af[i][0], bf01[j][0], acc[i][j], 0, 0, 0);
        acc[i][j] = __builtin_amdgcn_mfma_f32_16x16x32_bf16(af[i][1], bf01[j][1], acc[i][j], 0, 0, 0);
      }
    __builtin_amdgcn_s_setprio(0);
    BARRIER();

    // ph2: read bf23 | stage Ah0(T+2)->buf0 | Q(i0-3,j2-3)
#pragma unroll
    for (int j = 0; j < 2; ++j) {
      const int b = bBase + ((2 + j) << 12);
      bf23[j][0] = *(const v8s*)(lds + b);
      bf23[j][1] = *(const v8s*)(lds + (b ^ 32));
    }
    gld16(pA + k2, lw);
    gld16(pA + rstep + k2, lw + 4096);
    BARRIER(); LGKM0();
    __builtin_amdgcn_s_setprio(1);
#pragma unroll
    for (int i = 0; i < 4; ++i)
#pragma unroll
      for (int j = 0; j < 2; ++j) {
        acc[i][2 + j] = __builtin_amdgcn_mfma_f32_16x16x32_bf16(af[i][0], bf23[j][0], acc[i][2 + j], 0, 0, 0);
        acc[i][2 + j] = __builtin_amdgcn_mfma_f32_16x16x32_bf16(af[i][1], bf23[j][1], acc[i][2 + j], 0, 0, 0);
      }
    __builtin_amdgcn_s_setprio(0);
    BARRIER();

    // ph3: read af47 | stage Bh0(T+2)->buf0 | Q(i4-7,j2-3)
#pragma unroll
    for (int i = 0; i < 4; ++i) {
      const int a = aBase + ((4 + i) << 11);
      af[i][0] = *(const v8s*)(lds + a);
      af[i][1] = *(const v8s*)(lds + (a ^ 32));
    }
    gld16(pB + k2, lw + 16384);
    gld16(pB + rstep + k2, lw + 20480);
    BARRIER(); LGKM0();
    __builtin_amdgcn_s_setprio(1);
#pragma unroll
    for (int i = 0; i < 4; ++i)
#pragma unroll
      for (int j = 0; j < 2; ++j) {
        acc[4 + i][2 + j] = __builtin_amdgcn_mfma_f32_16x16x32_bf16(af[i][0], bf23[j][0], acc[4 + i][2 + j], 0, 0, 0);
        acc[4 + i][2 + j] = __builtin_amdgcn_mfma_f32_16x16x32_bf16(af[i][1], bf23[j][1], acc[4 + i][2 + j], 0, 0, 0);
      }
    __builtin_amdgcn_s_setprio(0);
    BARRIER();

    // ph4: stage Bh1(T+2)->buf0 | Q(i4-7,j0-1) | VMC6 (T+1 landed)
    gld16(pB + hstep + k2, lw + 24576);
    gld16(pB + hstep + rstep + k2, lw + 28672);
    BARRIER();
    __builtin_amdgcn_s_setprio(1);
#pragma unroll
    for (int i = 0; i < 4; ++i)
#pragma unroll
      for (int j = 0; j < 2; ++j) {
        acc[4 + i][j] = __builtin_amdgcn_mfma_f32_16x16x32_bf16(af[i][0], bf01[j][0], acc[4 + i][j], 0, 0, 0);
        acc[4 + i][j] = __builtin_amdgcn_mfma_f32_16x16x32_bf16(af[i][1], bf01[j][1], acc[4 + i][j], 0, 0, 0);
      }
    __builtin_amdgcn_s_setprio(0);
    VMC6();
    BARRIER();

    // ================= tile T+1 (buf1) =================
    // ph5: read af03+bf01 | stage Ah1(T+2)->buf0 | Q(i0-3,j0-1)
#pragma unroll
    for (int i = 0; i < 4; ++i) {
      const int a = 32768 + aBase + (i << 11);
      af[i][0] = *(const v8s*)(lds + a);
      af[i][1] = *(const v8s*)(lds + (a ^ 32));
    }
#pragma unroll
    for (int j = 0; j < 2; ++j) {
      const int b = 32768 + bBase + (j << 12);
      bf01[j][0] = *(const v8s*)(lds + b);
      bf01[j][1] = *(const v8s*)(lds + (b ^ 32));
    }
    gld16(pA + hstep + k2, lw + 8192);
    gld16(pA + hstep + rstep + k2, lw + 12288);
    BARRIER(); LGKM0();
    __builtin_amdgcn_s_setprio(1);
#pragma unroll
    for (int i = 0; i < 4; ++i)
#pragma unroll
      for (int j = 0; j < 2; ++j) {
        acc[i][j] = __builtin_amdgcn_mfma_f32_16x16x32_bf16(af[i][0], bf01[j][0], acc[i][j], 0, 0, 0);
        acc[i][j] = __builtin_amdgcn_mfma_f32_16x16x32_bf16(af[i][1], bf01[j][1], acc[i][j], 0, 0, 0);
      }
    __builtin_amdgcn_s_setprio(0);
    BARRIER();

    // ph6: read bf23 | stage Ah0(T+3)->buf1 | Q(i0-3,j2-3)
#pragma unroll
    for (int j = 0; j < 2; ++j) {
      const int b = 32768 + bBase + ((2 + j) << 12);
      bf23[j][0] = *(const v8s*)(lds + b);
      bf23[j][1] = *(const v8s*)(lds + (b ^ 32));
    }
    gld16(pA + k3, lw + 32768);
    gld16(pA + rstep + k3, lw + 32768 + 4096);
    BARRIER(); LGKM0();
    __builtin_amdgcn_s_setprio(1);
#pragma unroll
    for (int i = 0; i < 4; ++i)
#pragma unroll
      for (int j = 0; j < 2; ++j) {
        acc[i][2 + j] = __builtin_amdgcn_mfma_f32_16x16x32_bf16(af[i][0], bf23[j][0], acc[i][2 + j], 0, 0, 0);
        acc[i][2 + j] = __builtin_amdgcn_mfma_f32_16x16x32_bf16(af[i][1], bf23[j][1], acc[i][2 + j], 0, 0, 0);
      }
    __builtin_amdgcn_s_setprio(0);
    BARRIER();

    // ph7: read af47 | stage Bh0(T+3)->buf1 | Q(i4-7,j2-3)
#pragma unroll
    for (int i = 0; i < 4; ++i) {
      const int a = 32768 + aBase + ((4 + i) << 11);
      af[i][0] = *(const v8s*)(lds + a);
      af[i][1] = *(const v8s*)(lds + (a ^ 32));
    }
    gld16(pB + k3, lw + 32768 + 16384);
    gld16(pB + rstep + k3, lw + 32768 + 20480);
    BARRIER(); LGKM0();
    __builtin_amdgcn_s_setprio(1);
#pragma unroll
    for (int i = 0; i < 4; ++i)
#pragma unroll
      for (int j = 0; j < 2; ++j) {
        acc[4 + i][2 + j] = __builtin_amdgcn_mfma_f32_16x16x32_bf16(af[i][0], bf23[j][0], acc[4 + i][2 + j], 0, 0, 0);
        acc[4 + i][2 + j] = __builtin_amdgcn_mfma_f32_16x16x32_bf16(af[i][1], bf23[j][1], acc[4 + i][2 + j], 0, 0, 0);
      }
    __builtin_amdgcn_s_setprio(0);
    BARRIER();

    // ph8: stage Bh1(T+3)->buf1 | Q(i4-7,j0-1) | VMC6 (T+2 landed)
    gld16(pB + hstep + k3, lw + 32768 + 24576);
    gld16(pB + hstep + rstep + k3, lw + 32768 + 28672);
    BARRIER();
    __builtin_amdgcn_s_setprio(1);
#pragma unroll
    for (int i = 0; i < 4; ++i)
#pragma unroll
      for (int j = 0; j < 2; ++j) {
        acc[4 + i][j] = __builtin_amdgcn_mfma_f32_16x16x32_bf16(af[i][0], bf01[j][0], acc[4 + i][j], 0, 0, 0);
        acc[4 + i][j] = __builtin_amdgcn_mfma_f32_16x16x32_bf16(af[i][1], bf01[j][1], acc[4 + i][j], 0, 0, 0);
      }
    __builtin_amdgcn_s_setprio(0);
    VMC6();
    BARRIER();
  }

  // ---------------- epilogue: 256c x 256m C-tile through LDS ----------------
  // fragment-interleaved mapping: m = i*32 + wm*16 + q*4 + r; c = j*64 + wn*16 + r16
  VMC0();
  __syncthreads();
#pragma unroll
  for (int i = 0; i < 8; ++i)
#pragma unroll
    for (int j = 0; j < 4; ++j) {
      const int cl = (j << 6) + (wn << 4) + r16;
      const int ml = (i << 5) + (wm << 4) + (q << 2);
      const int phys = (cl << 8) + ((((ml >> 3) ^ (cl & 7)) << 3) | (ml & 7));
      uint2 pv;
      pv.x = pk2(acc[i][j][0], acc[i][j][1]);
      pv.y = pk2(acc[i][j][2], acc[i][j][3]);
      *(uint2*)(lds + phys) = pv;
    }
  __syncthreads();
#pragma unroll
  for (int it = 0; it < 16; ++it) {
    const int f = (it << 9) + t;
    const int cl = f >> 5, sl = f & 31;
    const int phys = (cl << 8) + ((sl ^ (cl & 7)) << 3);
    union { uint4 v; u16 e[8]; } tv;
    tv.v = *(const uint4*)(lds + phys);
    const u64 gi = (u64)(c0 + cl) * NN + m0 + (sl << 3);
    if (Xt) {
      union { uint4 v; u16 e[8]; } xv, ov;
      xv.v = *(const uint4*)(Xt + gi);
#pragma unroll
      for (int s = 0; s < 8; ++s) ov.e[s] = f2b(2.f * b2f(tv.e[s]) - b2f(xv.e[s]));
      *(uint4*)(Ct + gi) = ov.v;
    } else {
      *(uint4*)(Ct + gi) = tv.v;
    }
  }
}

// ---------------------------------------------------------------------------
// gemm192 (R6 verified): 256x192 tile for layer-0. BK=64, 8 waves (2Mx4N,
// per-wave 128x48, acc[8][3]), 2-barrier free-run schedule, vmcnt(3).
// grid (16, 12), block 512.
// ---------------------------------------------------------------------------
__global__ __launch_bounds__(512, 2) void gemm192(const u16* __restrict__ A,
                                                  const u16* __restrict__ B,
                                                  u16* __restrict__ Ct,
                                                  const u16* __restrict__ Xt) {
  // 2 bufs x 28672 u16: A [256][64] at 0 | B [192][64] at 16384
  __shared__ __align__(16) u16 lds[57344];
  const int t = threadIdx.x;
  const int wave = t >> 6, lane = t & 63;
  const int q = lane >> 4, r16 = lane & 15;
  const int wm = wave >> 2, wn = wave & 3;

  const int nwg = (int)(gridDim.x * gridDim.y);   // 192, % 8 == 0
  const int bid = (int)(blockIdx.y * gridDim.x + blockIdx.x);
  const int swz = (bid & 7) * (nwg >> 3) + (bid >> 3);
  const int m0 = (swz & 15) << 8;                 // gridDim.x == 16
  const int c0 = (swz >> 4) * 192;                // 0..11

  v4f acc[8][3];
  const v4f vz = {0.f, 0.f, 0.f, 0.f};
#pragma unroll
  for (int i = 0; i < 8; ++i)
#pragma unroll
    for (int j = 0; j < 3; ++j) acc[i][j] = vz;

  const int srow = t >> 3;
  const int sslot = ((t & 7) ^ (srow & 7)) << 3;
  const u16* pA = A + (u64)(m0 + srow) * NN + sslot;
  const u16* pB = B + (u64)(c0 + srow) * NN + sslot;
  const u64 rstep = (u64)64 * NN;
  u16* lw = lds + (wave << 9);

  const int sw8 = (q ^ (r16 & 7)) << 3;
  const int aBase = (wm << 13) + (r16 << 6) + sw8;               // + i<<10
  const int bBase = 16384 + wn * 3072 + (r16 << 6) + sw8;        // + j<<10

  const int NT = NN >> 6;  // 64 K-tiles

  // prologue: A(0) 4 ops, B(0) 3 ops, B(1) 3 ops; VMC3 leaves B(1) in flight
  gld16(pA, lw);
  gld16(pA + rstep, lw + 4096);
  gld16(pA + 2 * rstep, lw + 8192);
  gld16(pA + 3 * rstep, lw + 12288);
  gld16(pB, lw + 16384);
  gld16(pB + rstep, lw + 20480);
  gld16(pB + 2 * rstep, lw + 24576);
  gld16(pB + 64, lw + 28672 + 16384);
  gld16(pB + 64 + rstep, lw + 28672 + 20480);
  gld16(pB + 64 + 2 * rstep, lw + 28672 + 24576);
  VMC3();
  BARRIER();

  v8s af[4][2], bf01[2][2], bf2[2];
#pragma unroll
  for (int i = 0; i < 4; ++i) {
    const int a = aBase + (i << 10);
    af[i][0] = *(const v8s*)(lds + a);
    af[i][1] = *(const v8s*)(lds + (a ^ 32));
  }
#pragma unroll
  for (int j = 0; j < 2; ++j) {
    const int b = bBase + (j << 10);
    bf01[j][0] = *(const v8s*)(lds + b);
    bf01[j][1] = *(const v8s*)(lds + (b ^ 32));
  }

#pragma unroll 2
  for (int T = 0; T < NT; ++T) {
    const int bo = (T & 1) ? 28672 : 0;
    const int no = bo ^ 28672;
    const u64 ka = (u64)(T + 1 < NT ? T + 1 : NT - 1) << 6;
    const u64 kb = (u64)(T + 2 < NT ? T + 2 : NT - 1) << 6;

    // ---- P0: stage A-h0(T+1) | read bf2 | MFMA af03 x bf01 (16)
    gld16(pA + ka, lw + no);
    gld16(pA + ka + rstep, lw + no + 4096);
    {
      const int b = bo + bBase + 2048;   // j = 2
      bf2[0] = *(const v8s*)(lds + b);
      bf2[1] = *(const v8s*)(lds + (b ^ 32));
    }
    __builtin_amdgcn_s_setprio(1);
#pragma unroll
    for (int i = 0; i < 4; ++i)
#pragma unroll
      for (int j = 0; j < 2; ++j) {
        acc[i][j] = __builtin_amdgcn_mfma_f32_16x16x32_bf16(af[i][0], bf01[j][0], acc[i][j], 0, 0, 0);
        acc[i][j] = __builtin_amdgcn_mfma_f32_16x16x32_bf16(af[i][1], bf01[j][1], acc[i][j], 0, 0, 0);
      }
    __builtin_amdgcn_s_setprio(0);

    // ---- P1: stage A-h1(T+1) | LGKM0 + BARRIER (B-region WAR) |
    //          MFMA af03 x bf2 (8) | read af47
    gld16(pA + ka + 2 * rstep, lw + no + 8192);
    gld16(pA + ka + 3 * rstep, lw + no + 12288);
    LGKM0();
    BARRIER();
    __builtin_amdgcn_s_setprio(1);
#pragma unroll
    for (int i = 0; i < 4; ++i) {
      acc[i][2] = __builtin_amdgcn_mfma_f32_16x16x32_bf16(af[i][0], bf2[0], acc[i][2], 0, 0, 0);
      acc[i][2] = __builtin_amdgcn_mfma_f32_16x16x32_bf16(af[i][1], bf2[1], acc[i][2], 0, 0, 0);
    }
    __builtin_amdgcn_s_setprio(0);
#pragma unroll
    for (int i = 0; i < 4; ++i) {
      const int a = bo + aBase + ((4 + i) << 10);
      af[i][0] = *(const v8s*)(lds + a);
      af[i][1] = *(const v8s*)(lds + (a ^ 32));
    }
    __builtin_amdgcn_sched_barrier(0);

    // ---- P2: stage B-r01(T+2) | MFMA af47 x bf2 (8)
    gld16(pB + kb, lw + bo + 16384);
    gld16(pB + kb + rstep, lw + bo + 20480);
    __builtin_amdgcn_s_setprio(1);
#pragma unroll
    for (int i = 0; i < 4; ++i) {
      acc[4 + i][2] = __builtin_amdgcn_mfma_f32_16x16x32_bf16(af[i][0], bf2[0], acc[4 + i][2], 0, 0, 0);
      acc[4 + i][2] = __builtin_amdgcn_mfma_f32_16x16x32_bf16(af[i][1], bf2[1], acc[4 + i][2], 0, 0, 0);
    }
    __builtin_amdgcn_s_setprio(0);

    // ---- P3: stage B-r2(T+2) | MFMA af47 x bf01 (16) | VMC3 + BARRIER | prefetch
    gld16(pB + kb + 2 * rstep, lw + bo + 24576);
    __builtin_amdgcn_s_setprio(1);
#pragma unroll
    for (int i = 0; i < 4; ++i)
#pragma unroll
      for (int j = 0; j < 2; ++j) {
        acc[4 + i][j] = __builtin_amdgcn_mfma_f32_16x16x32_bf16(af[i][0], bf01[j][0], acc[4 + i][j], 0, 0, 0);
        acc[4 + i][j] = __builtin_amdgcn_mfma_f32_16x16x32_bf16(af[i][1], bf01[j][1], acc[4 + i][j], 0, 0, 0);
      }
    __builtin_amdgcn_s_setprio(0);
    VMC3();   // drains A(T+1) (and all earlier); leaves B(T+2)'s 3 ops in flight
    BARRIER();
#pragma unroll
    for (int i = 0; i < 4; ++i) {
      const int a = no + aBase + (i << 10);
      af[i][0] = *(const v8s*)(lds + a);
      af[i][1] = *(const v8s*)(lds + (a ^ 32));
    }
#pragma unroll
    for (int j = 0; j < 2; ++j) {
      const int b = no + bBase + (j << 10);
      bf01[j][0] = *(const v8s*)(lds + b);
      bf01[j][1] = *(const v8s*)(lds + (b ^ 32));
    }
    __builtin_amdgcn_sched_barrier(0);
  }

  // ---------------- epilogue: 192c x 256m through LDS ----------------
  VMC0();
  __syncthreads();
#pragma unroll
  for (int i = 0; i < 8; ++i)
#pragma unroll
    for (int j = 0; j < 3; ++j) {
      const int cl = wn * 48 + j * 16 + r16;                 // 0..191
      const int ml = (wm << 7) + (i << 4) + (q << 2);        // 0..255
      const int phys = (cl << 8) + ((((ml >> 3) ^ (cl & 7)) << 3) | (ml & 7));
      uint2 pv;
      pv.x = pk2(acc[i][j][0], acc[i][j][1]);
      pv.y = pk2(acc[i][j][2], acc[i][j][3]);
      *(uint2*)(lds + phys) = pv;
    }
  __syncthreads();
#pragma unroll
  for (int it = 0; it < 12; ++it) {
    const int f = (it << 9) + t;
    const int cl = f >> 5, sl = f & 31;
    const int phys = (cl << 8) + ((sl ^ (cl & 7)) << 3);
    union { uint4 v; u16 e[8]; } tv;
    tv.v = *(const uint4*)(lds + phys);
    const u64 gi = (u64)(c0 + cl) * NN + m0 + (sl << 3);
    if (Xt) {
      union { uint4 v; u16 e[8]; } xv, ov;
      xv.v = *(const uint4*)(Xt + gi);
#pragma unroll
      for (int s = 0; s < 8; ++s) ov.e[s] = f2b(2.f * b2f(tv.e[s]) - b2f(xv.e[s]));
      *(uint4*)(Ct + gi) = ov.v;
    } else {
      *(uint4*)(Ct + gi) = tv.v;
    }
  }
}

// ---------------------------------------------------------------------------
// gemm_s (fallback if workspace too small for bf16 S): A f32, in-loop cvt.
// ---------------------------------------------------------------------------
__global__ __launch_bounds__(256) void gemm_s(const float* __restrict__ A,
                                              const u16* __restrict__ B,
                                              u16* __restrict__ Ct,
                                              const u16* __restrict__ Xt) {
  __shared__ __align__(16) u16 As[4096];
  __shared__ __align__(16) u16 Bs[4096];
  __shared__ __align__(16) u16 T[16384];
  const int t = threadIdx.x;
  const int wave = t >> 6, lane = t & 63;
  const int m0 = blockIdx.x << 7, c0 = blockIdx.y << 7;
  const int wm = (wave >> 1) << 6, wc = (wave & 1) << 6;
  const int q = lane >> 4, r16 = lane & 15;
  v4f acc[4][4];
  const v4f vz = {0.f, 0.f, 0.f, 0.f};
#pragma unroll
  for (int i = 0; i < 4; ++i)
#pragma unroll
    for (int j = 0; j < 4; ++j) acc[i][j] = vz;

  const int sr = t >> 2;
  const int sc = (t & 3) << 3;
  const u64 abase = (u64)(m0 + sr) * NN + sc;
  const u64 bbase = (u64)(c0 + sr) * NN + sc;
  const u64 rstep = (u64)64 * NN;
  u16* as0 = As + sr * 32 + sc;
  u16* as1 = As + (64 + sr) * 32 + sc;
  u16* bs0 = Bs + sr * 32 + sc;
  u16* bs1 = Bs + (64 + sr) * 32 + sc;

  for (int k0 = 0; k0 < NN; k0 += 32) {
    const float4 a0l = *(const float4*)(A + abase + k0);
    const float4 a0h = *(const float4*)(A + abase + k0 + 4);
    const float4 a1l = *(const float4*)(A + abase + rstep + k0);
    const float4 a1h = *(const float4*)(A + abase + rstep + k0 + 4);
    const uint4 b0 = *(const uint4*)(B + bbase + k0);
    const uint4 b1 = *(const uint4*)(B + bbase + rstep + k0);
    uint4 pa0, pa1;
    pa0.x = pk2(a0l.x, a0l.y); pa0.y = pk2(a0l.z, a0l.w);
    pa0.z = pk2(a0h.x, a0h.y); pa0.w = pk2(a0h.z, a0h.w);
    pa1.x = pk2(a1l.x, a1l.y); pa1.y = pk2(a1l.z, a1l.w);
    pa1.z = pk2(a1h.x, a1h.y); pa1.w = pk2(a1h.z, a1h.w);
    __syncthreads();
    *(uint4*)as0 = pa0;
    *(uint4*)as1 = pa1;
    *(uint4*)bs0 = b0;
    *(uint4*)bs1 = b1;
    __syncthreads();
    v8s af[4], bf[4];
#pragma unroll
    for (int i = 0; i < 4; ++i)
      af[i] = *(const v8s*)(As + ((wm + i * 16 + r16) << 5) + (q << 3));
#pragma unroll
    for (int j = 0; j < 4; ++j)
      bf[j] = *(const v8s*)(Bs + ((wc + j * 16 + r16) << 5) + (q << 3));
#pragma unroll
    for (int i = 0; i < 4; ++i)
#pragma unroll
      for (int j = 0; j < 4; ++j)
        acc[i][j] = __builtin_amdgcn_mfma_f32_16x16x32_bf16(af[i], bf[j], acc[i][j], 0, 0, 0);
  }
#pragma unroll
  for (int i = 0; i < 4; ++i)
#pragma unroll
    for (int j = 0; j < 4; ++j) {
      const int cl = wc + j * 16 + r16;
      const int mm = wm + i * 16 + (q << 2);
      uint2 pv;
      pv.x = pk2(acc[i][j][0], acc[i][j][1]);
      pv.y = pk2(acc[i][j][2], acc[i][j][3]);
      *(uint2*)(T + (cl << 7) + mm) = pv;
    }
  __syncthreads();
#pragma unroll
  for (int it = 0; it < 8; ++it) {
    const int flat = it * 256 + t;
    const int cl = flat >> 4;
    const int seg = (flat & 15) << 3;
    const u64 gi = (u64)(c0 + cl) * NN + m0 + seg;
    union { uint4 v; u16 e[8]; } tv;
    tv.v = *(uint4*)(T + (cl << 7) + seg);
    if (Xt) {
      union { uint4 v; u16 e[8]; } xv, ov;
      xv.v = *(const uint4*)(Xt + gi);
#pragma unroll
      for (int s = 0; s < 8; ++s) ov.e[s] = f2b(2.f * b2f(tv.e[s]) - b2f(xv.e[s]));
      *(uint4*)(Ct + gi) = ov.v;
    } else {
      *(uint4*)(Ct + gi) = tv.v;
    }
  }
}

// ---------------------------------------------------------------------------
// Projection: out[b*JSTR + j][n] = act( sum_k Wt[j][k] * F[row(k,b)][n] + b[j] )
// ---------------------------------------------------------------------------
template <int DP, int KTOT>
__global__ __launch_bounds__(256) void proj_k(const u16* __restrict__ Wt,
                                              const u16* __restrict__ F,
                                              const float* __restrict__ bias,
                                              u16* __restrict__ outp,
                                              const int JSTR, const int ACT) {
  __shared__ __align__(16) u16 As2[2048];  // 64 j x 32 k
  __shared__ __align__(16) u16 Bs2[4096];  // 32 k x 128 n
  const int t = threadIdx.x;
  const int wave = t >> 6, lane = t & 63;
  const int q = lane >> 4, r16 = lane & 15;
  const int n0 = blockIdx.x << 7;
  const int j0 = blockIdx.y << 6;
  const int b = blockIdx.z;
  v4f acc[4][2];
  const v4f vz = {0.f, 0.f, 0.f, 0.f};
#pragma unroll
  for (int i = 0; i < 4; ++i) { acc[i][0] = vz; acc[i][1] = vz; }

  const int ar = t >> 2, ac = (t & 3) << 3;
  const u64 wbase = (u64)(j0 + ar) * KTOT + ac;

  for (int k0 = 0; k0 < KTOT; k0 += 32) {
    const uint4 av = *(const uint4*)(Wt + wbase + k0);
    uint4 bv[2];
#pragma unroll
    for (int ci = 0; ci < 2; ++ci) {
      const int c = ci * 256 + t;
      const int kr = c >> 4;
      const int seg = (c & 15) << 3;
      const int kk = k0 + kr;
      const int i = kk / DP;
      const int d = kk - i * DP;
      bv[ci] = *(const uint4*)(F + ((u64)i * (BATCH * DP) + (u64)b * DP + d) * NN + n0 + seg);
    }
    __syncthreads();
    *(uint4*)(As2 + ar * 32 + ac) = av;
#pragma unroll
    for (int ci = 0; ci < 2; ++ci) {
      const int c = ci * 256 + t;
      const int kr = c >> 4;
      const int seg = (c & 15) << 3;
      *(uint4*)(Bs2 + (kr << 7) + seg) = bv[ci];
    }
    __syncthreads();
    v8s af[4], bf[2];
#pragma unroll
    for (int i = 0; i < 4; ++i)
      af[i] = *(const v8s*)(As2 + ((i * 16 + r16) << 5) + (q << 3));
#pragma unroll
    for (int jj = 0; jj < 2; ++jj) {
      const int nn = (wave << 5) + jj * 16 + r16;
      v8s v;
#pragma unroll
      for (int s = 0; s < 8; ++s) v[s] = (short)Bs2[(((q << 3) + s) << 7) + nn];
      bf[jj] = v;
    }
#pragma unroll
    for (int i = 0; i < 4; ++i)
#pragma unroll
      for (int jj = 0; jj < 2; ++jj)
        acc[i][jj] = __builtin_amdgcn_mfma_f32_16x16x32_bf16(af[i], bf[jj], acc[i][jj], 0, 0, 0);
  }
#pragma unroll
  for (int i = 0; i < 4; ++i)
#pragma unroll
    for (int jj = 0; jj < 2; ++jj)
#pragma unroll
      for (int r = 0; r < 4; ++r) {
        const int j = j0 + i * 16 + (q << 2) + r;
        const int n = n0 + (wave << 5) + jj * 16 + r16;
        float v = acc[i][jj][r] + bias[j];
        v = ACT ? (1.f - 2.f / (__expf(2.f * v) + 1.f)) : (1.f / (1.f + __expf(-v)));
        outp[((u64)b * JSTR + j) * NN + n] = f2b(v);
      }
}

// ---------------------------------------------------------------------------
__global__ __launch_bounds__(256) void repackW(const float* __restrict__ W, u16* __restrict__ Wt,
                                               const int D, const int DP, const int KTOT,
                                               const int J) {
  const int idx = blockIdx.x * 256 + threadIdx.x;
  if (idx >= J * KTOT) return;
  const int j = idx / KTOT, k = idx - j * KTOT;
  const int i = k / DP, d = k - i * DP;
  u16 v = 0;
  if (i < 5 && d < D) v = f2b(W[(i * D + d) * J + j]);
  Wt[idx] = v;
}

// ---------------------------------------------------------------------------
__global__ __launch_bounds__(256) void pack0(const float* __restrict__ x,
                                             const float* __restrict__ hid0,
                                             u16* __restrict__ F0) {
  __shared__ __align__(16) u16 Hs[64 * 72];
  const int b = blockIdx.y, n0 = blockIdx.x << 6, t = threadIdx.x;
  const int r = t >> 2, ds = t & 3;
  const float* hrow = hid0 + ((u64)b * NN + n0 + r) * 64;
#pragma unroll
  for (int c4 = 0; c4 < 4; ++c4) {
    const float4 v = *(const float4*)(hrow + ds * 16 + c4 * 4);
    uint2 p;
    p.x = pk2(v.x, v.y);
    p.y = pk2(v.z, v.w);
    *(uint2*)(Hs + r * 72 + ds * 16 + c4 * 4) = p;
  }
  __syncthreads();
#pragma unroll
  for (int c2 = 0; c2 < 2; ++c2) {
    union { uint4 v; u16 h[8]; } o;
#pragma unroll
    for (int s = 0; s < 8; ++s) o.h[s] = Hs[(ds * 16 + c2 * 8 + s) * 72 + r];
    *(uint4*)(F0 + ((u64)b * 72 + 1 + r) * NN + n0 + ds * 16 + c2 * 8) = o.v;
  }
  if (t < 64) {
    F0[(u64)b * 72 * NN + n0 + t] = f2b(x[(u64)b * NN + n0 + t]);
  } else if (t < 120) {
    const int tt = t - 64;
    const int row = 65 + (tt >> 3), seg = (tt & 7) << 3;
    uint4 z; z.x = z.y = z.z = z.w = 0;
    *(uint4*)(F0 + ((u64)b * 72 + row) * NN + n0 + seg) = z;
  }
}

// ---------------------------------------------------------------------------
__global__ __launch_bounds__(256) void pack1(const float* __restrict__ hid1,
                                             u16* __restrict__ F1) {
  __shared__ __align__(16) u16 Hs[64 * 72];
  const int b = blockIdx.y, n0 = blockIdx.x << 6, t = threadIdx.x;
  const int r = t >> 2, ds = t & 3;
  const float* hrow = hid1 + ((u64)b * NN + n0 + r) * 64;
#pragma unroll
  for (int c4 = 0; c4 < 4; ++c4) {
    const float4 v = *(const float4*)(hrow + ds * 16 + c4 * 4);
    uint2 p;
    p.x = pk2(v.x, v.y);
    p.y = pk2(v.z, v.w);
    *(uint2*)(Hs + r * 72 + ds * 16 + c4 * 4) = p;
  }
  __syncthreads();
#pragma unroll
  for (int c2 = 0; c2 < 2; ++c2) {
    union { uint4 v; u16 h[8]; } o;
#pragma unroll
    for (int s = 0; s < 8; ++s) o.h[s] = Hs[(ds * 16 + c2 * 8 + s) * 72 + r];
    *(uint4*)(F1 + ((u64)b * 128 + 64 + r) * NN + n0 + ds * 16 + c2 * 8) = o.v;
  }
}

// ---------------------------------------------------------------------------
__global__ __launch_bounds__(256) void candpack(const u16* __restrict__ G, u16* __restrict__ F,
                                                const int DP, const int OFF) {
  const int u = blockIdx.x * 256 + threadIdx.x;
  const int b = u >> 15;
  const int d = (u >> 9) & 63;
  const int seg = (u & 511) << 3;
  union { uint4 v; u16 h[8]; } g, f, o;
  g.v = *(const uint4*)(G + ((u64)b * 128 + d) * NN + seg);
  u16* fp = F + ((u64)b * DP + OFF + d) * NN + seg;
  f.v = *(const uint4*)fp;
#pragma unroll
  for (int s = 0; s < 8; ++s) o.h[s] = f2b(b2f(f.h[s]) * b2f(g.h[s]));
  *(uint4*)fp = o.v;
}

// ---------------------------------------------------------------------------
__global__ __launch_bounds__(256) void hnew_k(const u16* __restrict__ G,
                                              const float* __restrict__ hidL,
                                              u16* __restrict__ HnF,
                                              float* __restrict__ outH) {
  __shared__ __align__(16) float Hs[64 * 72];
  __shared__ __align__(16) float T2[64 * 72];
  const int b = blockIdx.y, n0 = blockIdx.x << 6, t = threadIdx.x;
  const int r = t >> 2, ds = t & 3;
  const float* hrow = hidL + ((u64)b * NN + n0 + r) * 64;
#pragma unroll
  for (int c4 = 0; c4 < 4; ++c4)
    *(float4*)(Hs + r * 72 + ds * 16 + c4 * 4) = *(const float4*)(hrow + ds * 16 + c4 * 4);
  __syncthreads();
#pragma unroll
  for (int c2 = 0; c2 < 2; ++c2) {
    const int ncol = ds * 16 + c2 * 8;
    union { uint4 v; u16 h[8]; } uv, cv, o;
    uv.v = *(const uint4*)(G + ((u64)b * 128 + 64 + r) * NN + n0 + ncol);
    cv.v = *(const uint4*)(G + ((u64)b * 128 + r) * NN + n0 + ncol);
#pragma unroll
    for (int s = 0; s < 8; ++s) {
      const int nl = ncol + s;
      const float uu = b2f(uv.h[s]);
      const float hh = Hs[nl * 72 + r];
      const float cc = b2f(cv.h[s]);
      const float v = uu * hh + (1.f - uu) * cc;
      o.h[s] = f2b(v);
      T2[nl * 72 + r] = v;
    }
    *(uint4*)(HnF + ((u64)b * 128 + r) * NN + n0 + ncol) = o.v;
  }
  __syncthreads();
  const int nl2 = t >> 2, dseg = (t & 3) << 4;
#pragma unroll
  for (int c4 = 0; c4 < 4; ++c4) {
    const float4 v = *(const float4*)(T2 + nl2 * 72 + dseg + c4 * 4);
    *(float4*)(outH + ((u64)b * NN + n0 + nl2) * 64 + dseg + c4 * 4) = v;
  }
}

// ---------------------------------------------------------------------------
__global__ __launch_bounds__(256) void predictk(const float* __restrict__ H1bnd,
                                                const float* __restrict__ Wp,
                                                const float* __restrict__ bp,
                                                float* __restrict__ outp) {
  __shared__ float w[64];
  __shared__ float bb;
  const int t = threadIdx.x;
  if (t < 64) w[t] = Wp[t];
  if (t == 64) bb = bp[0];
  __syncthreads();
  const int idx = blockIdx.x * 256 + t;
  const float* h = H1bnd + (u64)idx * 64;
  float acc = bb;
#pragma unroll
  for (int c4 = 0; c4 < 16; ++c4) {
    const float4 v = *(const float4*)(h + c4 * 4);
    acc += v.x * w[c4 * 4] + v.y * w[c4 * 4 + 1] + v.z * w[c4 * 4 + 2] + v.w * w[c4 * 4 + 3];
  }
  outp[idx] = acc;
}

extern "C" void kernel_launch(void* const* d_in, const int* in_sizes, int n_in,
                              void* d_out, int out_size, void* d_ws, size_t ws_size,
                              hipStream_t stream) {
  const float* X   = (const float*)d_in[0];
  const float* HID = (const float*)d_in[1];
  const float* Sf  = (const float*)d_in[2];
  const float* Sb  = (const float*)d_in[3];
  const float* Wg0 = (const float*)d_in[4];
  const float* bg0 = (const float*)d_in[5];
  const float* Wc0 = (const float*)d_in[6];
  const float* bc0 = (const float*)d_in[7];
  const float* Wg1 = (const float*)d_in[8];
  const float* bg1 = (const float*)d_in[9];
  const float* Wc1 = (const float*)d_in[10];
  const float* bc1 = (const float*)d_in[11];
  const float* Wp  = (const float*)d_in[12];
  const float* bp  = (const float*)d_in[13];
  float* OUT = (float*)d_out;
  char* ws = (char*)d_ws;

  u16* F = (u16*)(ws);
  u16* G = (u16*)(ws + 167772160ull);
  const u64 NEED_BIG = 167772160ull + 33554432ull + 2ull * 33554432ull + 393216ull;
  const bool big = ws_size >= NEED_BIG;
  u16* Sfb = (u16*)(ws + 167772160ull + 33554432ull);
  u16* Sbb = Sfb + (u64)NN * NN;
  u16* WT = big ? (Sbb + (u64)NN * NN)
                : (u16*)(ws + 167772160ull + 33554432ull);
  u16* Wg0t = WT;                   // 128 x 384
  u16* Wc0t = Wg0t + 128 * 384;     // 64 x 384
  u16* Wg1t = Wc0t + 64 * 384;      // 128 x 640
  u16* Wc1t = Wg1t + 128 * 640;     // 64 x 640

  const float* HID1 = HID + (u64)32 * 4096 * 64;
  float* OUT_H0 = OUT + 131072;
  float* OUT_H1 = OUT + 131072 + 8388608;

  // zero the layer-0 K-padding region of F (rows 11520..13823), read by proj i=5
  hipMemsetAsync(ws + (u64)11520 * NN * 2, 0, (u64)2304 * NN * 2, stream);

  if (big) {
    cvtS<<<8192, 256, 0, stream>>>(Sf, Sfb);
    cvtS<<<8192, 256, 0, stream>>>(Sb, Sbb);
  }

  repackW<<<(128 * 384 + 255) / 256, 256, 0, stream>>>(Wg0, Wg0t, 65, 72, 384, 128);
  repackW<<<(64 * 384 + 255) / 256, 256, 0, stream>>>(Wc0, Wc0t, 65, 72, 384, 64);
  repackW<<<(128 * 640 + 255) / 256, 256, 0, stream>>>(Wg1, Wg1t, 128, 128, 640, 128);
  repackW<<<(64 * 640 + 255) / 256, 256, 0, stream>>>(Wc1, Wc1t, 128, 128, 640, 64);

  // ---------------- layer 0 (Dp=72, C=2304) ----------------
  pack0<<<dim3(64, 32), 256, 0, stream>>>(X, HID, F);
  const u64 R0 = (u64)2304 * NN;
  const dim3 g192(16, 12);
  if (big) {
    gemm192<<<g192, 512, 0, stream>>>(Sfb, F, F + R0, nullptr);
    gemm192<<<g192, 512, 0, stream>>>(Sbb, F, F + 3 * R0, nullptr);
    gemm192<<<g192, 512, 0, stream>>>(Sfb, F + R0, F + 2 * R0, F);
    gemm192<<<g192, 512, 0, stream>>>(Sbb, F + 3 * R0, F + 4 * R0, F);
  } else {
    gemm_s<<<dim3(32, 18), 256, 0, stream>>>(Sf, F, F + R0, nullptr);
    gemm_s<<<dim3(32, 18), 256, 0, stream>>>(Sb, F, F + 3 * R0, nullptr);
    gemm_s<<<dim3(32, 18), 256, 0, stream>>>(Sf, F + R0, F + 2 * R0, F);
    gemm_s<<<dim3(32, 18), 256, 0, stream>>>(Sb, F + 3 * R0, F + 4 * R0, F);
  }
  proj_k<72, 384><<<dim3(32, 2, 32), 256, 0, stream>>>(Wg0t, F, bg0, G, 128, 0);
  candpack<<<4096, 256, 0, stream>>>(G, F, 72, 1);
  if (big) {
    gemm192<<<g192, 512, 0, stream>>>(Sfb, F, F + R0, nullptr);
    gemm192<<<g192, 512, 0, stream>>>(Sbb, F, F + 3 * R0, nullptr);
    gemm192<<<g192, 512, 0, stream>>>(Sfb, F + R0, F + 2 * R0, F);
    gemm192<<<g192, 512, 0, stream>>>(Sbb, F + 3 * R0, F + 4 * R0, F);
  } else {
    gemm_s<<<dim3(32, 18), 256, 0, stream>>>(Sf, F, F + R0, nullptr);
    gemm_s<<<dim3(32, 18), 256, 0, stream>>>(Sb, F, F + 3 * R0, nullptr);
    gemm_s<<<dim3(32, 18), 256, 0, stream>>>(Sf, F + R0, F + 2 * R0, F);
    gemm_s<<<dim3(32, 18), 256, 0, stream>>>(Sb, F + 3 * R0, F + 4 * R0, F);
  }
  proj_k<72, 384><<<dim3(32, 1, 32), 256, 0, stream>>>(Wc0t, F, bc0, G, 128, 1);
  hnew_k<<<dim3(64, 32), 256, 0, stream>>>(G, HID, F, OUT_H0);

  // ---------------- layer 1 (Dp=128, C=4096) ----------------
  pack1<<<dim3(64, 32), 256, 0, stream>>>(HID1, F);
  const u64 R1 = (u64)4096 * NN;
  const dim3 g256(16, 16);
  if (big) {
    gemm256<<<g256, 512, 0, stream>>>(Sfb, F, F + R1, nullptr);
    gemm256<<<g256, 512, 0, stream>>>(Sbb, F, F + 3 * R1, nullptr);
    gemm256<<<g256, 512, 0, stream>>>(Sfb, F + R1, F + 2 * R1, F);
    gemm256<<<g256, 512, 0, stream>>>(Sbb, F + 3 * R1, F + 4 * R1, F);
  } else {
    gemm_s<<<dim3(32, 32), 256, 0, stream>>>(Sf, F, F + R1, nullptr);
    gemm_s<<<dim3(32, 32), 256, 0, stream>>>(Sb, F, F + 3 * R1, nullptr);
    gemm_s<<<dim3(32, 32), 256, 0, stream>>>(Sf, F + R1, F + 2 * R1, F);
    gemm_s<<<dim3(32, 32), 256, 0, stream>>>(Sb, F + 3 * R1, F + 4 * R1, F);
  }
  proj_k<128, 640><<<dim3(32, 2, 32), 256, 0, stream>>>(Wg1t, F, bg1, G, 128, 0);
  candpack<<<4096, 256, 0, stream>>>(G, F, 128, 64);
  if (big) {
    gemm256<<<g256, 512, 0, stream>>>(Sfb, F, F + R1, nullptr);
    gemm256<<<g256, 512, 0, stream>>>(Sbb, F, F + 3 * R1, nullptr);
    gemm256<<<g256, 512, 0, stream>>>(Sfb, F + R1, F + 2 * R1, F);
    gemm256<<<g256, 512, 0, stream>>>(Sbb, F + 3 * R1, F + 4 * R1, F);
  } else {
    gemm_s<<<dim3(32, 32), 256, 0, stream>>>(Sf, F, F + R1, nullptr);
    gemm_s<<<dim3(32, 32), 256, 0, stream>>>(Sb, F, F + 3 * R1, nullptr);
    gemm_s<<<dim3(32, 32), 256, 0, stream>>>(Sf, F + R1, F + 2 * R1, F);
    gemm_s<<<dim3(32, 32), 256, 0, stream>>>(Sb, F + 3 * R1, F + 4 * R1, F);
  }
  proj_k<128, 640><<<dim3(32, 1, 32), 256, 0, stream>>>(Wc1t, F, bc1, G, 128, 1);
  hnew_k<<<dim3(64, 32), 256, 0, stream>>>(G, HID1, F, OUT_H1);

  predictk<<<512, 256, 0, stream>>>(OUT_H1, Wp, bp, OUT);
}

// Round 9
// 1935.148 us; speedup vs baseline: 1.0251x; 1.0251x over previous
//
#include <hip/hip_runtime.h>

typedef unsigned short u16;
typedef unsigned int u32;
typedef unsigned long long u64;
typedef short v8s __attribute__((ext_vector_type(8)));
typedef float v4f __attribute__((ext_vector_type(4)));

#define NN 4096
#define BATCH 32

__device__ __forceinline__ float b2f(u16 u) {
  union { u32 i; float f; } c; c.i = ((u32)u) << 16; return c.f;
}
__device__ __forceinline__ u16 f2b(float f) {
  union { float f; u32 i; } c; c.f = f;
  u32 x = c.i;
  return (u16)((x + 0x7fffu + ((x >> 16) & 1u)) >> 16);
}
__device__ __forceinline__ u32 pk2(float a, float b) {
  return (u32)f2b(a) | ((u32)f2b(b) << 16);
}

typedef const __attribute__((address_space(1))) u32* gp_t;
typedef __attribute__((address_space(3))) u32* lp_t;
__device__ __forceinline__ void gld16(const u16* g, u16* l) {
  __builtin_amdgcn_global_load_lds((gp_t)g, (lp_t)l, 16, 0, 0);
}

#define CBAR() asm volatile("" ::: "memory")
#define BARRIER() do { CBAR(); __builtin_amdgcn_s_barrier(); CBAR(); } while (0)
#define LGKM0() asm volatile("s_waitcnt lgkmcnt(0)" ::: "memory")
#define VMC4() asm volatile("s_waitcnt vmcnt(4)" ::: "memory")
#define VMC3() asm volatile("s_waitcnt vmcnt(3)" ::: "memory")
#define VMC0() asm volatile("s_waitcnt vmcnt(0)" ::: "memory")

// ---------------------------------------------------------------------------
// cvtS: f32 -> bf16 (RNE), 8 elems/thread. grid: 8192 x 256 for 16.8M elems.
// ---------------------------------------------------------------------------
__global__ __launch_bounds__(256) void cvtS(const float* __restrict__ S,
                                            u16* __restrict__ Sb) {
  const u64 idx = ((u64)blockIdx.x * 256 + threadIdx.x) * 8;
  const float4 a = *(const float4*)(S + idx);
  const float4 b = *(const float4*)(S + idx + 4);
  uint4 o;
  o.x = pk2(a.x, a.y); o.y = pk2(a.z, a.w);
  o.z = pk2(b.x, b.y); o.w = pk2(b.z, b.w);
  *(uint4*)(Sb + idx) = o;
}

// ---------------------------------------------------------------------------
// gemm256 (R3/R6 verified, 104.7us): 256x256 tile, BK=64, 8 waves (2Mx4N).
// Minimal-barrier free-run schedule + one-cluster-ahead operand pipelining.
// grid (16, C/256), block 512.
// ---------------------------------------------------------------------------
__global__ __launch_bounds__(512, 2) void gemm256(const u16* __restrict__ A,
                                                  const u16* __restrict__ B,
                                                  u16* __restrict__ Ct,
                                                  const u16* __restrict__ Xt) {
  // 128 KiB: buf b at b*32768 (u16); regions A-h0 0 | A-h1 8192 | B-h0 16384 | B-h1 24576
  __shared__ __align__(16) u16 lds[65536];
  const int t = threadIdx.x;
  const int wave = t >> 6, lane = t & 63;
  const int q = lane >> 4, r16 = lane & 15;
  const int wm = wave >> 2, wn = wave & 3;

  const int nwg = (int)(gridDim.x * gridDim.y);
  const int bid = (int)(blockIdx.y * gridDim.x + blockIdx.x);
  const int swz = (bid & 7) * (nwg >> 3) + (bid >> 3);
  const int m0 = (swz & 15) << 8;   // gridDim.x == 16 always
  const int c0 = (swz >> 4) << 8;

  v4f acc[8][4];
  const v4f vz = {0.f, 0.f, 0.f, 0.f};
#pragma unroll
  for (int i = 0; i < 8; ++i)
#pragma unroll
    for (int j = 0; j < 4; ++j) acc[i][j] = vz;

  const int srow = t >> 3;
  const int sslot = ((t & 7) ^ (srow & 7)) << 3;      // element col offset
  const u16* pA = A + (u64)(m0 + srow) * NN + sslot;
  const u16* pB = B + (u64)(c0 + srow) * NN + sslot;
  const u64 rstep = (u64)64 * NN;
  const u64 hstep = (u64)128 * NN;
  u16* lw = lds + (wave << 9);

  const int sw8 = (q ^ (r16 & 7)) << 3;
  const int aBase = (wm << 13) + (r16 << 6) + sw8;
  const int bBase = 16384 + ((wn >> 1) << 13) + ((wn & 1) << 12) + (r16 << 6) + sw8;

  const int NT = NN >> 6;  // 64 K-tiles

  gld16(pA, lw);
  gld16(pA + rstep, lw + 4096);
  gld16(pA + hstep, lw + 8192);
  gld16(pA + hstep + rstep, lw + 12288);
  gld16(pB, lw + 16384);
  gld16(pB + rstep, lw + 20480);
  gld16(pB + hstep, lw + 24576);
  gld16(pB + hstep + rstep, lw + 28672);
  gld16(pB + 64, lw + 32768 + 16384);
  gld16(pB + 64 + rstep, lw + 32768 + 20480);
  gld16(pB + 64 + hstep, lw + 32768 + 24576);
  gld16(pB + 64 + hstep + rstep, lw + 32768 + 28672);
  VMC4();
  BARRIER();

  v8s af[4][2], bf01[2][2], bf23[2][2];
#pragma unroll
  for (int i = 0; i < 4; ++i) {
    const int a = aBase + (i << 10);
    af[i][0] = *(const v8s*)(lds + a);
    af[i][1] = *(const v8s*)(lds + (a ^ 32));
  }
#pragma unroll
  for (int j = 0; j < 2; ++j) {
    const int b = bBase + (j << 10);
    bf01[j][0] = *(const v8s*)(lds + b);
    bf01[j][1] = *(const v8s*)(lds + (b ^ 32));
  }

#pragma unroll 2
  for (int T = 0; T < NT; ++T) {
    const int bo = (T & 1) << 15;
    const int no = bo ^ 32768;
    const u64 ka = (u64)(T + 1 < NT ? T + 1 : NT - 1) << 6;
    const u64 kb = (u64)(T + 2 < NT ? T + 2 : NT - 1) << 6;

    // ---- phase 0
    gld16(pA + ka, lw + no);
    gld16(pA + ka + rstep, lw + no + 4096);
#pragma unroll
    for (int j = 0; j < 2; ++j) {
      const int b = bo + bBase + ((2 + j) << 10);
      bf23[j][0] = *(const v8s*)(lds + b);
      bf23[j][1] = *(const v8s*)(lds + (b ^ 32));
    }
    __builtin_amdgcn_s_setprio(1);
#pragma unroll
    for (int i = 0; i < 4; ++i)
#pragma unroll
      for (int j = 0; j < 2; ++j) {
        acc[i][j] = __builtin_amdgcn_mfma_f32_16x16x32_bf16(af[i][0], bf01[j][0], acc[i][j], 0, 0, 0);
        acc[i][j] = __builtin_amdgcn_mfma_f32_16x16x32_bf16(af[i][1], bf01[j][1], acc[i][j], 0, 0, 0);
      }
    __builtin_amdgcn_s_setprio(0);

    // ---- phase 1
    gld16(pA + hstep + ka, lw + no + 8192);
    gld16(pA + hstep + ka + rstep, lw + no + 12288);
    LGKM0();
    BARRIER();
    __builtin_amdgcn_s_setprio(1);
#pragma unroll
    for (int i = 0; i < 4; ++i)
#pragma unroll
      for (int j = 0; j < 2; ++j) {
        acc[i][2 + j] = __builtin_amdgcn_mfma_f32_16x16x32_bf16(af[i][0], bf23[j][0], acc[i][2 + j], 0, 0, 0);
        acc[i][2 + j] = __builtin_amdgcn_mfma_f32_16x16x32_bf16(af[i][1], bf23[j][1], acc[i][2 + j], 0, 0, 0);
      }
    __builtin_amdgcn_s_setprio(0);
#pragma unroll
    for (int i = 0; i < 4; ++i) {
      const int a = bo + aBase + ((4 + i) << 10);
      af[i][0] = *(const v8s*)(lds + a);
      af[i][1] = *(const v8s*)(lds + (a ^ 32));
    }
    __builtin_amdgcn_sched_barrier(0);

    // ---- phase 2
    gld16(pB + kb, lw + bo + 16384);
    gld16(pB + kb + rstep, lw + bo + 20480);
    __builtin_amdgcn_s_setprio(1);
#pragma unroll
    for (int i = 0; i < 4; ++i)
#pragma unroll
      for (int j = 0; j < 2; ++j) {
        acc[4 + i][2 + j] = __builtin_amdgcn_mfma_f32_16x16x32_bf16(af[i][0], bf23[j][0], acc[4 + i][2 + j], 0, 0, 0);
        acc[4 + i][2 + j] = __builtin_amdgcn_mfma_f32_16x16x32_bf16(af[i][1], bf23[j][1], acc[4 + i][2 + j], 0, 0, 0);
      }
    __builtin_amdgcn_s_setprio(0);

    // ---- phase 3
    gld16(pB + hstep + kb, lw + bo + 24576);
    gld16(pB + hstep + rstep + kb, lw + bo + 28672);
    VMC4();
    BARRIER();
    __builtin_amdgcn_s_setprio(1);
#pragma unroll
    for (int i = 0; i < 4; ++i)
#pragma unroll
      for (int j = 0; j < 2; ++j) {
        acc[4 + i][j] = __builtin_amdgcn_mfma_f32_16x16x32_bf16(af[i][0], bf01[j][0], acc[4 + i][j], 0, 0, 0);
        acc[4 + i][j] = __builtin_amdgcn_mfma_f32_16x16x32_bf16(af[i][1], bf01[j][1], acc[4 + i][j], 0, 0, 0);
      }
    __builtin_amdgcn_s_setprio(0);
#pragma unroll
    for (int i = 0; i < 4; ++i) {
      const int a = no + aBase + (i << 10);
      af[i][0] = *(const v8s*)(lds + a);
      af[i][1] = *(const v8s*)(lds + (a ^ 32));
    }
#pragma unroll
    for (int j = 0; j < 2; ++j) {
      const int b = no + bBase + (j << 10);
      bf01[j][0] = *(const v8s*)(lds + b);
      bf01[j][1] = *(const v8s*)(lds + (b ^ 32));
    }
    __builtin_amdgcn_sched_barrier(0);
  }

  // ---------------- epilogue ----------------
  VMC0();
  __syncthreads();
#pragma unroll
  for (int i = 0; i < 8; ++i)
#pragma unroll
    for (int j = 0; j < 4; ++j) {
      const int cl = (wn << 6) + (j << 4) + r16;
      const int ml = (wm << 7) + (i << 4) + (q << 2);
      const int phys = (cl << 8) + ((((ml >> 3) ^ (cl & 7)) << 3) | (ml & 7));
      uint2 pv;
      pv.x = pk2(acc[i][j][0], acc[i][j][1]);
      pv.y = pk2(acc[i][j][2], acc[i][j][3]);
      *(uint2*)(lds + phys) = pv;
    }
  __syncthreads();
#pragma unroll
  for (int it = 0; it < 16; ++it) {
    const int f = (it << 9) + t;
    const int cl = f >> 5, sl = f & 31;
    const int phys = (cl << 8) + ((sl ^ (cl & 7)) << 3);
    union { uint4 v; u16 e[8]; } tv;
    tv.v = *(const uint4*)(lds + phys);
    const u64 gi = (u64)(c0 + cl) * NN + m0 + (sl << 3);
    if (Xt) {
      union { uint4 v; u16 e[8]; } xv, ov;
      xv.v = *(const uint4*)(Xt + gi);
#pragma unroll
      for (int s = 0; s < 8; ++s) ov.e[s] = f2b(2.f * b2f(tv.e[s]) - b2f(xv.e[s]));
      *(uint4*)(Ct + gi) = ov.v;
    } else {
      *(uint4*)(Ct + gi) = tv.v;
    }
  }
}

// ---------------------------------------------------------------------------
// gemm144: 256x144 tile for layer-0 (C=2304 -> 16x16 = 256 blocks, exact CU
// fill with 0.5625-size blocks). Identical staging/hazard/LDS skeleton to the
// verified R6 gemm192 (A=4 stage-ops, B=3 ops with rows 144..191 padded-
// never-read, vmcnt(3), 2 barriers/tile). Wave mapping 8Mx1N: per-wave 32x144
// (acc[2][9], af[2], bfA=bf[0..4] prefetched, bfB=bf[5..8] read in P0).
// grid (16, 16), block 512.
// ---------------------------------------------------------------------------
__global__ __launch_bounds__(512, 2) void gemm144(const u16* __restrict__ A,
                                                  const u16* __restrict__ B,
                                                  u16* __restrict__ Ct,
                                                  const u16* __restrict__ Xt) {
  // 2 bufs x 28672 u16: A [256][64] at 0 | B [192][64] at 16384
  __shared__ __align__(16) u16 lds[57344];
  const int t = threadIdx.x;
  const int wave = t >> 6, lane = t & 63;
  const int q = lane >> 4, r16 = lane & 15;
  const int wm = wave;                     // 8M x 1N

  const int nwg = (int)(gridDim.x * gridDim.y);   // 256
  const int bid = (int)(blockIdx.y * gridDim.x + blockIdx.x);
  const int swz = (bid & 7) * (nwg >> 3) + (bid >> 3);
  const int m0 = (swz & 15) << 8;                 // gridDim.x == 16
  const int c0 = (swz >> 4) * 144;                // 0..15

  v4f acc[2][9];
  const v4f vz = {0.f, 0.f, 0.f, 0.f};
#pragma unroll
  for (int i = 0; i < 2; ++i)
#pragma unroll
    for (int j = 0; j < 9; ++j) acc[i][j] = vz;

  const int srow = t >> 3;
  const int sslot = ((t & 7) ^ (srow & 7)) << 3;
  const u16* pA = A + (u64)(m0 + srow) * NN + sslot;
  const u16* pB = B + (u64)(c0 + srow) * NN + sslot;  // rows 144..191 slack
  const u64 rstep = (u64)64 * NN;
  u16* lw = lds + (wave << 9);

  const int sw8 = (q ^ (r16 & 7)) << 3;
  const int aBase = (wm << 11) + (r16 << 6) + sw8;        // + i<<10
  const int bBase = 16384 + (r16 << 6) + sw8;             // + j<<10

  const int NT = NN >> 6;  // 64 K-tiles

  // prologue: A(0) 4 ops, B(0) 3 ops, B(1) 3 ops; VMC3 leaves B(1) in flight
  gld16(pA, lw);
  gld16(pA + rstep, lw + 4096);
  gld16(pA + 2 * rstep, lw + 8192);
  gld16(pA + 3 * rstep, lw + 12288);
  gld16(pB, lw + 16384);
  gld16(pB + rstep, lw + 20480);
  gld16(pB + 2 * rstep, lw + 24576);
  gld16(pB + 64, lw + 28672 + 16384);
  gld16(pB + 64 + rstep, lw + 28672 + 20480);
  gld16(pB + 64 + 2 * rstep, lw + 28672 + 24576);
  VMC3();
  BARRIER();

  v8s af[2][2], bfA[5][2], bfB[4][2];
#pragma unroll
  for (int i = 0; i < 2; ++i) {
    const int a = aBase + (i << 10);
    af[i][0] = *(const v8s*)(lds + a);
    af[i][1] = *(const v8s*)(lds + (a ^ 32));
  }
#pragma unroll
  for (int j = 0; j < 5; ++j) {
    const int b = bBase + (j << 10);
    bfA[j][0] = *(const v8s*)(lds + b);
    bfA[j][1] = *(const v8s*)(lds + (b ^ 32));
  }

#pragma unroll 2
  for (int T = 0; T < NT; ++T) {
    const int bo = (T & 1) ? 28672 : 0;
    const int no = bo ^ 28672;
    const u64 ka = (u64)(T + 1 < NT ? T + 1 : NT - 1) << 6;
    const u64 kb = (u64)(T + 2 < NT ? T + 2 : NT - 1) << 6;

    // ---- P0: stage A ops0-1 (T+1) | read bfB | MFMA af x bfA ks0 (10)
    gld16(pA + ka, lw + no);
    gld16(pA + ka + rstep, lw + no + 4096);
#pragma unroll
    for (int j = 0; j < 4; ++j) {
      const int b = bo + bBase + ((5 + j) << 10);
      bfB[j][0] = *(const v8s*)(lds + b);
      bfB[j][1] = *(const v8s*)(lds + (b ^ 32));
    }
    __builtin_amdgcn_s_setprio(1);
#pragma unroll
    for (int i = 0; i < 2; ++i)
#pragma unroll
      for (int j = 0; j < 5; ++j)
        acc[i][j] = __builtin_amdgcn_mfma_f32_16x16x32_bf16(af[i][0], bfA[j][0], acc[i][j], 0, 0, 0);
    __builtin_amdgcn_s_setprio(0);

    // ---- P1: stage A ops2-3 (T+1) | LGKM0 + BARRIER (region WAR) |
    //          MFMA af x bfA ks1 (10)
    gld16(pA + ka + 2 * rstep, lw + no + 8192);
    gld16(pA + ka + 3 * rstep, lw + no + 12288);
    LGKM0();
    BARRIER();
    __builtin_amdgcn_s_setprio(1);
#pragma unroll
    for (int i = 0; i < 2; ++i)
#pragma unroll
      for (int j = 0; j < 5; ++j)
        acc[i][j] = __builtin_amdgcn_mfma_f32_16x16x32_bf16(af[i][1], bfA[j][1], acc[i][j], 0, 0, 0);
    __builtin_amdgcn_s_setprio(0);

    // ---- P2: stage B ops0-1 (T+2) -> bo | MFMA af x bfB ks0 (8)
    gld16(pB + kb, lw + bo + 16384);
    gld16(pB + kb + rstep, lw + bo + 20480);
    __builtin_amdgcn_s_setprio(1);
#pragma unroll
    for (int i = 0; i < 2; ++i)
#pragma unroll
      for (int j = 0; j < 4; ++j)
        acc[i][5 + j] = __builtin_amdgcn_mfma_f32_16x16x32_bf16(af[i][0], bfB[j][0], acc[i][5 + j], 0, 0, 0);
    __builtin_amdgcn_s_setprio(0);

    // ---- P3: stage B op2 (T+2) | MFMA af x bfB ks1 (8) | VMC3 + BARRIER |
    //          prefetch af, bfA from no-buf
    gld16(pB + kb + 2 * rstep, lw + bo + 24576);
    __builtin_amdgcn_s_setprio(1);
#pragma unroll
    for (int i = 0; i < 2; ++i)
#pragma unroll
      for (int j = 0; j < 4; ++j)
        acc[i][5 + j] = __builtin_amdgcn_mfma_f32_16x16x32_bf16(af[i][1], bfB[j][1], acc[i][5 + j], 0, 0, 0);
    __builtin_amdgcn_s_setprio(0);
    VMC3();   // drains A(T+1)+B(T+1); leaves B(T+2)'s 3 ops in flight
    BARRIER();
#pragma unroll
    for (int i = 0; i < 2; ++i) {
      const int a = no + aBase + (i << 10);
      af[i][0] = *(const v8s*)(lds + a);
      af[i][1] = *(const v8s*)(lds + (a ^ 32));
    }
#pragma unroll
    for (int j = 0; j < 5; ++j) {
      const int b = no + bBase + (j << 10);
      bfA[j][0] = *(const v8s*)(lds + b);
      bfA[j][1] = *(const v8s*)(lds + (b ^ 32));
    }
    __builtin_amdgcn_sched_barrier(0);
  }

  // ---------------- epilogue: 144c x 256m through LDS ----------------
  VMC0();
  __syncthreads();
#pragma unroll
  for (int i = 0; i < 2; ++i)
#pragma unroll
    for (int j = 0; j < 9; ++j) {
      const int cl = j * 16 + r16;                           // 0..143
      const int ml = (wm << 5) + (i << 4) + (q << 2);        // 0..252
      const int phys = (cl << 8) + ((((ml >> 3) ^ (cl & 7)) << 3) | (ml & 7));
      uint2 pv;
      pv.x = pk2(acc[i][j][0], acc[i][j][1]);
      pv.y = pk2(acc[i][j][2], acc[i][j][3]);
      *(uint2*)(lds + phys) = pv;
    }
  __syncthreads();
#pragma unroll
  for (int it = 0; it < 9; ++it) {
    const int f = (it << 9) + t;
    const int cl = f >> 5, sl = f & 31;                      // cl 0..143
    const int phys = (cl << 8) + ((sl ^ (cl & 7)) << 3);
    union { uint4 v; u16 e[8]; } tv;
    tv.v = *(const uint4*)(lds + phys);
    const u64 gi = (u64)(c0 + cl) * NN + m0 + (sl << 3);
    if (Xt) {
      union { uint4 v; u16 e[8]; } xv, ov;
      xv.v = *(const uint4*)(Xt + gi);
#pragma unroll
      for (int s = 0; s < 8; ++s) ov.e[s] = f2b(2.f * b2f(tv.e[s]) - b2f(xv.e[s]));
      *(uint4*)(Ct + gi) = ov.v;
    } else {
      *(uint4*)(Ct + gi) = tv.v;
    }
  }
}

// ---------------------------------------------------------------------------
// gemm_s (fallback if workspace too small for bf16 S): A f32, in-loop cvt.
// ---------------------------------------------------------------------------
__global__ __launch_bounds__(256) void gemm_s(const float* __restrict__ A,
                                              const u16* __restrict__ B,
                                              u16* __restrict__ Ct,
                                              const u16* __restrict__ Xt) {
  __shared__ __align__(16) u16 As[4096];
  __shared__ __align__(16) u16 Bs[4096];
  __shared__ __align__(16) u16 T[16384];
  const int t = threadIdx.x;
  const int wave = t >> 6, lane = t & 63;
  const int m0 = blockIdx.x << 7, c0 = blockIdx.y << 7;
  const int wm = (wave >> 1) << 6, wc = (wave & 1) << 6;
  const int q = lane >> 4, r16 = lane & 15;
  v4f acc[4][4];
  const v4f vz = {0.f, 0.f, 0.f, 0.f};
#pragma unroll
  for (int i = 0; i < 4; ++i)
#pragma unroll
    for (int j = 0; j < 4; ++j) acc[i][j] = vz;

  const int sr = t >> 2;
  const int sc = (t & 3) << 3;
  const u64 abase = (u64)(m0 + sr) * NN + sc;
  const u64 bbase = (u64)(c0 + sr) * NN + sc;
  const u64 rstep = (u64)64 * NN;
  u16* as0 = As + sr * 32 + sc;
  u16* as1 = As + (64 + sr) * 32 + sc;
  u16* bs0 = Bs + sr * 32 + sc;
  u16* bs1 = Bs + (64 + sr) * 32 + sc;

  for (int k0 = 0; k0 < NN; k0 += 32) {
    const float4 a0l = *(const float4*)(A + abase + k0);
    const float4 a0h = *(const float4*)(A + abase + k0 + 4);
    const float4 a1l = *(const float4*)(A + abase + rstep + k0);
    const float4 a1h = *(const float4*)(A + abase + rstep + k0 + 4);
    const uint4 b0 = *(const uint4*)(B + bbase + k0);
    const uint4 b1 = *(const uint4*)(B + bbase + rstep + k0);
    uint4 pa0, pa1;
    pa0.x = pk2(a0l.x, a0l.y); pa0.y = pk2(a0l.z, a0l.w);
    pa0.z = pk2(a0h.x, a0h.y); pa0.w = pk2(a0h.z, a0h.w);
    pa1.x = pk2(a1l.x, a1l.y); pa1.y = pk2(a1l.z, a1l.w);
    pa1.z = pk2(a1h.x, a1h.y); pa1.w = pk2(a1h.z, a1h.w);
    __syncthreads();
    *(uint4*)as0 = pa0;
    *(uint4*)as1 = pa1;
    *(uint4*)bs0 = b0;
    *(uint4*)bs1 = b1;
    __syncthreads();
    v8s af[4], bf[4];
#pragma unroll
    for (int i = 0; i < 4; ++i)
      af[i] = *(const v8s*)(As + ((wm + i * 16 + r16) << 5) + (q << 3));
#pragma unroll
    for (int j = 0; j < 4; ++j)
      bf[j] = *(const v8s*)(Bs + ((wc + j * 16 + r16) << 5) + (q << 3));
#pragma unroll
    for (int i = 0; i < 4; ++i)
#pragma unroll
      for (int j = 0; j < 4; ++j)
        acc[i][j] = __builtin_amdgcn_mfma_f32_16x16x32_bf16(af[i], bf[j], acc[i][j], 0, 0, 0);
  }
#pragma unroll
  for (int i = 0; i < 4; ++i)
#pragma unroll
    for (int j = 0; j < 4; ++j) {
      const int cl = wc + j * 16 + r16;
      const int mm = wm + i * 16 + (q << 2);
      uint2 pv;
      pv.x = pk2(acc[i][j][0], acc[i][j][1]);
      pv.y = pk2(acc[i][j][2], acc[i][j][3]);
      *(uint2*)(T + (cl << 7) + mm) = pv;
    }
  __syncthreads();
#pragma unroll
  for (int it = 0; it < 8; ++it) {
    const int flat = it * 256 + t;
    const int cl = flat >> 4;
    const int seg = (flat & 15) << 3;
    const u64 gi = (u64)(c0 + cl) * NN + m0 + seg;
    union { uint4 v; u16 e[8]; } tv;
    tv.v = *(uint4*)(T + (cl << 7) + seg);
    if (Xt) {
      union { uint4 v; u16 e[8]; } xv, ov;
      xv.v = *(const uint4*)(Xt + gi);
#pragma unroll
      for (int s = 0; s < 8; ++s) ov.e[s] = f2b(2.f * b2f(tv.e[s]) - b2f(xv.e[s]));
      *(uint4*)(Ct + gi) = ov.v;
    } else {
      *(uint4*)(Ct + gi) = tv.v;
    }
  }
}

// ---------------------------------------------------------------------------
// Projection: v = sum_k Wt[j][k] * F[row(k,b)][n] + b[j]; act(v).
// If Fmul != null and j < 64 (gate r): F[b*DP+OFF+j][n] *= act(v)  (fused
// candpack). Else write act(v) to outp[b*JSTR + j][n].
// ---------------------------------------------------------------------------
template <int DP, int KTOT>
__global__ __launch_bounds__(256) void proj_k(const u16* __restrict__ Wt,
                                              const u16* __restrict__ F,
                                              const float* __restrict__ bias,
                                              u16* __restrict__ outp,
                                              const int JSTR, const int ACT,
                                              u16* __restrict__ Fmul,
                                              const int OFF) {
  __shared__ __align__(16) u16 As2[2048];  // 64 j x 32 k
  __shared__ __align__(16) u16 Bs2[4096];  // 32 k x 128 n
  const int t = threadIdx.x;
  const int wave = t >> 6, lane = t & 63;
  const int q = lane >> 4, r16 = lane & 15;
  const int n0 = blockIdx.x << 7;
  const int j0 = blockIdx.y << 6;
  const int b = blockIdx.z;
  v4f acc[4][2];
  const v4f vz = {0.f, 0.f, 0.f, 0.f};
#pragma unroll
  for (int i = 0; i < 4; ++i) { acc[i][0] = vz; acc[i][1] = vz; }

  const int ar = t >> 2, ac = (t & 3) << 3;
  const u64 wbase = (u64)(j0 + ar) * KTOT + ac;

  for (int k0 = 0; k0 < KTOT; k0 += 32) {
    const uint4 av = *(const uint4*)(Wt + wbase + k0);
    uint4 bv[2];
#pragma unroll
    for (int ci = 0; ci < 2; ++ci) {
      const int c = ci * 256 + t;
      const int kr = c >> 4;
      const int seg = (c & 15) << 3;
      const int kk = k0 + kr;
      const int i = kk / DP;
      const int d = kk - i * DP;
      bv[ci] = *(const uint4*)(F + ((u64)i * (BATCH * DP) + (u64)b * DP + d) * NN + n0 + seg);
    }
    __syncthreads();
    *(uint4*)(As2 + ar * 32 + ac) = av;
#pragma unroll
    for (int ci = 0; ci < 2; ++ci) {
      const int c = ci * 256 + t;
      const int kr = c >> 4;
      const int seg = (c & 15) << 3;
      *(uint4*)(Bs2 + (kr << 7) + seg) = bv[ci];
    }
    __syncthreads();
    v8s af[4], bf[2];
#pragma unroll
    for (int i = 0; i < 4; ++i)
      af[i] = *(const v8s*)(As2 + ((i * 16 + r16) << 5) + (q << 3));
#pragma unroll
    for (int jj = 0; jj < 2; ++jj) {
      const int nn = (wave << 5) + jj * 16 + r16;
      v8s v;
#pragma unroll
      for (int s = 0; s < 8; ++s) v[s] = (short)Bs2[(((q << 3) + s) << 7) + nn];
      bf[jj] = v;
    }
#pragma unroll
    for (int i = 0; i < 4; ++i)
#pragma unroll
      for (int jj = 0; jj < 2; ++jj)
        acc[i][jj] = __builtin_amdgcn_mfma_f32_16x16x32_bf16(af[i], bf[jj], acc[i][jj], 0, 0, 0);
  }
#pragma unroll
  for (int i = 0; i < 4; ++i)
#pragma unroll
    for (int jj = 0; jj < 2; ++jj)
#pragma unroll
      for (int r = 0; r < 4; ++r) {
        const int j = j0 + i * 16 + (q << 2) + r;
        const int n = n0 + (wave << 5) + jj * 16 + r16;
        float v = acc[i][jj][r] + bias[j];
        v = ACT ? (1.f - 2.f / (__expf(2.f * v) + 1.f)) : (1.f / (1.f + __expf(-v)));
        if (Fmul && j < 64) {
          u16* fp = Fmul + ((u64)b * DP + OFF + j) * NN + n;
          *fp = f2b(b2f(*fp) * v);
        } else {
          outp[((u64)b * JSTR + j) * NN + n] = f2b(v);
        }
      }
}

// ---------------------------------------------------------------------------
__global__ __launch_bounds__(256) void repackW(const float* __restrict__ W, u16* __restrict__ Wt,
                                               const int D, const int DP, const int KTOT,
                                               const int J) {
  const int idx = blockIdx.x * 256 + threadIdx.x;
  if (idx >= J * KTOT) return;
  const int j = idx / KTOT, k = idx - j * KTOT;
  const int i = k / DP, d = k - i * DP;
  u16 v = 0;
  if (i < 5 && d < D) v = f2b(W[(i * D + d) * J + j]);
  Wt[idx] = v;
}

// ---------------------------------------------------------------------------
__global__ __launch_bounds__(256) void pack0(const float* __restrict__ x,
                                             const float* __restrict__ hid0,
                                             u16* __restrict__ F0) {
  __shared__ __align__(16) u16 Hs[64 * 72];
  const int b = blockIdx.y, n0 = blockIdx.x << 6, t = threadIdx.x;
  const int r = t >> 2, ds = t & 3;
  const float* hrow = hid0 + ((u64)b * NN + n0 + r) * 64;
#pragma unroll
  for (int c4 = 0; c4 < 4; ++c4) {
    const float4 v = *(const float4*)(hrow + ds * 16 + c4 * 4);
    uint2 p;
    p.x = pk2(v.x, v.y);
    p.y = pk2(v.z, v.w);
    *(uint2*)(Hs + r * 72 + ds * 16 + c4 * 4) = p;
  }
  __syncthreads();
#pragma unroll
  for (int c2 = 0; c2 < 2; ++c2) {
    union { uint4 v; u16 h[8]; } o;
#pragma unroll
    for (int s = 0; s < 8; ++s) o.h[s] = Hs[(ds * 16 + c2 * 8 + s) * 72 + r];
    *(uint4*)(F0 + ((u64)b * 72 + 1 + r) * NN + n0 + ds * 16 + c2 * 8) = o.v;
  }
  if (t < 64) {
    F0[(u64)b * 72 * NN + n0 + t] = f2b(x[(u64)b * NN + n0 + t]);
  } else if (t < 120) {
    const int tt = t - 64;
    const int row = 65 + (tt >> 3), seg = (tt & 7) << 3;
    uint4 z; z.x = z.y = z.z = z.w = 0;
    *(uint4*)(F0 + ((u64)b * 72 + row) * NN + n0 + seg) = z;
  }
}

// ---------------------------------------------------------------------------
__global__ __launch_bounds__(256) void pack1(const float* __restrict__ hid1,
                                             u16* __restrict__ F1) {
  __shared__ __align__(16) u16 Hs[64 * 72];
  const int b = blockIdx.y, n0 = blockIdx.x << 6, t = threadIdx.x;
  const int r = t >> 2, ds = t & 3;
  const float* hrow = hid1 + ((u64)b * NN + n0 + r) * 64;
#pragma unroll
  for (int c4 = 0; c4 < 4; ++c4) {
    const float4 v = *(const float4*)(hrow + ds * 16 + c4 * 4);
    uint2 p;
    p.x = pk2(v.x, v.y);
    p.y = pk2(v.z, v.w);
    *(uint2*)(Hs + r * 72 + ds * 16 + c4 * 4) = p;
  }
  __syncthreads();
#pragma unroll
  for (int c2 = 0; c2 < 2; ++c2) {
    union { uint4 v; u16 h[8]; } o;
#pragma unroll
    for (int s = 0; s < 8; ++s) o.h[s] = Hs[(ds * 16 + c2 * 8 + s) * 72 + r];
    *(uint4*)(F1 + ((u64)b * 128 + 64 + r) * NN + n0 + ds * 16 + c2 * 8) = o.v;
  }
}

// ---------------------------------------------------------------------------
// hnew_k: h' = u*h + (1-u)*c ; writes HnF (bf16 rows) and outH (f32 [b][n][64]).
// If outPred != null (layer 1): also fused predict — outPred[b*NN+n] =
// sum_d h'[n][d]*Wp[d] + bp  (T2 holds full d-range per block).
// ---------------------------------------------------------------------------
__global__ __launch_bounds__(256) void hnew_k(const u16* __restrict__ G,
                                              const float* __restrict__ hidL,
                                              u16* __restrict__ HnF,
                                              float* __restrict__ outH,
                                              const float* __restrict__ Wp,
                                              const float* __restrict__ bp,
                                              float* __restrict__ outPred) {
  __shared__ __align__(16) float Hs[64 * 72];
  __shared__ __align__(16) float T2[64 * 72];
  __shared__ float wsh[64];
  __shared__ float bbs;
  const int b = blockIdx.y, n0 = blockIdx.x << 6, t = threadIdx.x;
  const int r = t >> 2, ds = t & 3;
  const float* hrow = hidL + ((u64)b * NN + n0 + r) * 64;
  if (outPred) {
    if (t < 64) wsh[t] = Wp[t];
    if (t == 64) bbs = bp[0];
  }
#pragma unroll
  for (int c4 = 0; c4 < 4; ++c4)
    *(float4*)(Hs + r * 72 + ds * 16 + c4 * 4) = *(const float4*)(hrow + ds * 16 + c4 * 4);
  __syncthreads();
#pragma unroll
  for (int c2 = 0; c2 < 2; ++c2) {
    const int ncol = ds * 16 + c2 * 8;
    union { uint4 v; u16 h[8]; } uv, cv, o;
    uv.v = *(const uint4*)(G + ((u64)b * 128 + 64 + r) * NN + n0 + ncol);
    cv.v = *(const uint4*)(G + ((u64)b * 128 + r) * NN + n0 + ncol);
#pragma unroll
    for (int s = 0; s < 8; ++s) {
      const int nl = ncol + s;
      const float uu = b2f(uv.h[s]);
      const float hh = Hs[nl * 72 + r];
      const float cc = b2f(cv.h[s]);
      const float v = uu * hh + (1.f - uu) * cc;
      o.h[s] = f2b(v);
      T2[nl * 72 + r] = v;
    }
    *(uint4*)(HnF + ((u64)b * 128 + r) * NN + n0 + ncol) = o.v;
  }
  __syncthreads();
  const int nl2 = t >> 2, dseg = (t & 3) << 4;
#pragma unroll
  for (int c4 = 0; c4 < 4; ++c4) {
    const float4 v = *(const float4*)(T2 + nl2 * 72 + dseg + c4 * 4);
    *(float4*)(outH + ((u64)b * NN + n0 + nl2) * 64 + dseg + c4 * 4) = v;
  }
  if (outPred && t < 64) {
    float s = bbs;
#pragma unroll
    for (int rr = 0; rr < 64; ++rr) s += T2[t * 72 + rr] * wsh[rr];
    outPred[(u64)b * NN + n0 + t] = s;
  }
}

extern "C" void kernel_launch(void* const* d_in, const int* in_sizes, int n_in,
                              void* d_out, int out_size, void* d_ws, size_t ws_size,
                              hipStream_t stream) {
  const float* X   = (const float*)d_in[0];
  const float* HID = (const float*)d_in[1];
  const float* Sf  = (const float*)d_in[2];
  const float* Sb  = (const float*)d_in[3];
  const float* Wg0 = (const float*)d_in[4];
  const float* bg0 = (const float*)d_in[5];
  const float* Wc0 = (const float*)d_in[6];
  const float* bc0 = (const float*)d_in[7];
  const float* Wg1 = (const float*)d_in[8];
  const float* bg1 = (const float*)d_in[9];
  const float* Wc1 = (const float*)d_in[10];
  const float* bc1 = (const float*)d_in[11];
  const float* Wp  = (const float*)d_in[12];
  const float* bp  = (const float*)d_in[13];
  float* OUT = (float*)d_out;
  char* ws = (char*)d_ws;

  u16* F = (u16*)(ws);
  u16* G = (u16*)(ws + 167772160ull);
  const u64 NEED_BIG = 167772160ull + 33554432ull + 2ull * 33554432ull + 393216ull;
  const bool big = ws_size >= NEED_BIG;
  u16* Sfb = (u16*)(ws + 167772160ull + 33554432ull);
  u16* Sbb = Sfb + (u64)NN * NN;
  u16* WT = big ? (Sbb + (u64)NN * NN)
                : (u16*)(ws + 167772160ull + 33554432ull);
  u16* Wg0t = WT;                   // 128 x 384
  u16* Wc0t = Wg0t + 128 * 384;     // 64 x 384
  u16* Wg1t = Wc0t + 64 * 384;      // 128 x 640
  u16* Wc1t = Wg1t + 128 * 640;     // 64 x 640

  const float* HID1 = HID + (u64)32 * 4096 * 64;
  float* OUT_H0 = OUT + 131072;
  float* OUT_H1 = OUT + 131072 + 8388608;

  // zero the layer-0 K-padding region of F (rows 11520..13823), read by proj i=5
  hipMemsetAsync(ws + (u64)11520 * NN * 2, 0, (u64)2304 * NN * 2, stream);

  if (big) {
    cvtS<<<8192, 256, 0, stream>>>(Sf, Sfb);
    cvtS<<<8192, 256, 0, stream>>>(Sb, Sbb);
  }

  repackW<<<(128 * 384 + 255) / 256, 256, 0, stream>>>(Wg0, Wg0t, 65, 72, 384, 128);
  repackW<<<(64 * 384 + 255) / 256, 256, 0, stream>>>(Wc0, Wc0t, 65, 72, 384, 64);
  repackW<<<(128 * 640 + 255) / 256, 256, 0, stream>>>(Wg1, Wg1t, 128, 128, 640, 128);
  repackW<<<(64 * 640 + 255) / 256, 256, 0, stream>>>(Wc1, Wc1t, 128, 128, 640, 64);

  // ---------------- layer 0 (Dp=72, C=2304) ----------------
  pack0<<<dim3(64, 32), 256, 0, stream>>>(X, HID, F);
  const u64 R0 = (u64)2304 * NN;
  const dim3 g144(16, 16);
  if (big) {
    gemm144<<<g144, 512, 0, stream>>>(Sfb, F, F + R0, nullptr);
    gemm144<<<g144, 512, 0, stream>>>(Sbb, F, F + 3 * R0, nullptr);
    gemm144<<<g144, 512, 0, stream>>>(Sfb, F + R0, F + 2 * R0, F);
    gemm144<<<g144, 512, 0, stream>>>(Sbb, F + 3 * R0, F + 4 * R0, F);
  } else {
    gemm_s<<<dim3(32, 18), 256, 0, stream>>>(Sf, F, F + R0, nullptr);
    gemm_s<<<dim3(32, 18), 256, 0, stream>>>(Sb, F, F + 3 * R0, nullptr);
    gemm_s<<<dim3(32, 18), 256, 0, stream>>>(Sf, F + R0, F + 2 * R0, F);
    gemm_s<<<dim3(32, 18), 256, 0, stream>>>(Sb, F + 3 * R0, F + 4 * R0, F);
  }
  // gate proj: j<64 fused r*h into F rows OFF=1; j>=64 writes u into G
  proj_k<72, 384><<<dim3(32, 2, 32), 256, 0, stream>>>(Wg0t, F, bg0, G, 128, 0, F, 1);
  if (big) {
    gemm144<<<g144, 512, 0, stream>>>(Sfb, F, F + R0, nullptr);
    gemm144<<<g144, 512, 0, stream>>>(Sbb, F, F + 3 * R0, nullptr);
    gemm144<<<g144, 512, 0, stream>>>(Sfb, F + R0, F + 2 * R0, F);
    gemm144<<<g144, 512, 0, stream>>>(Sbb, F + 3 * R0, F + 4 * R0, F);
  } else {
    gemm_s<<<dim3(32, 18), 256, 0, stream>>>(Sf, F, F + R0, nullptr);
    gemm_s<<<dim3(32, 18), 256, 0, stream>>>(Sb, F, F + 3 * R0, nullptr);
    gemm_s<<<dim3(32, 18), 256, 0, stream>>>(Sf, F + R0, F + 2 * R0, F);
    gemm_s<<<dim3(32, 18), 256, 0, stream>>>(Sb, F + 3 * R0, F + 4 * R0, F);
  }
  proj_k<72, 384><<<dim3(32, 1, 32), 256, 0, stream>>>(Wc0t, F, bc0, G, 128, 1, nullptr, 0);
  hnew_k<<<dim3(64, 32), 256, 0, stream>>>(G, HID, F, OUT_H0, nullptr, nullptr, nullptr);

  // ---------------- layer 1 (Dp=128, C=4096) ----------------
  pack1<<<dim3(64, 32), 256, 0, stream>>>(HID1, F);
  const u64 R1 = (u64)4096 * NN;
  const dim3 g256(16, 16);
  if (big) {
    gemm256<<<g256, 512, 0, stream>>>(Sfb, F, F + R1, nullptr);
    gemm256<<<g256, 512, 0, stream>>>(Sbb, F, F + 3 * R1, nullptr);
    gemm256<<<g256, 512, 0, stream>>>(Sfb, F + R1, F + 2 * R1, F);
    gemm256<<<g256, 512, 0, stream>>>(Sbb, F + 3 * R1, F + 4 * R1, F);
  } else {
    gemm_s<<<dim3(32, 32), 256, 0, stream>>>(Sf, F, F + R1, nullptr);
    gemm_s<<<dim3(32, 32), 256, 0, stream>>>(Sb, F, F + 3 * R1, nullptr);
    gemm_s<<<dim3(32, 32), 256, 0, stream>>>(Sf, F + R1, F + 2 * R1, F);
    gemm_s<<<dim3(32, 32), 256, 0, stream>>>(Sb, F + 3 * R1, F + 4 * R1, F);
  }
  proj_k<128, 640><<<dim3(32, 2, 32), 256, 0, stream>>>(Wg1t, F, bg1, G, 128, 0, F, 64);
  if (big) {
    gemm256<<<g256, 512, 0, stream>>>(Sfb, F, F + R1, nullptr);
    gemm256<<<g256, 512, 0, stream>>>(Sbb, F, F + 3 * R1, nullptr);
    gemm256<<<g256, 512, 0, stream>>>(Sfb, F + R1, F + 2 * R1, F);
    gemm256<<<g256, 512, 0, stream>>>(Sbb, F + 3 * R1, F + 4 * R1, F);
  } else {
    gemm_s<<<dim3(32, 32), 256, 0, stream>>>(Sf, F, F + R1, nullptr);
    gemm_s<<<dim3(32, 32), 256, 0, stream>>>(Sb, F, F + 3 * R1, nullptr);
    gemm_s<<<dim3(32, 32), 256, 0, stream>>>(Sf, F + R1, F + 2 * R1, F);
    gemm_s<<<dim3(32, 32), 256, 0, stream>>>(Sb, F + 3 * R1, F + 4 * R1, F);
  }
  proj_k<128, 640><<<dim3(32, 1, 32), 256, 0, stream>>>(Wc1t, F, bc1, G, 128, 1, nullptr, 0);
  hnew_k<<<dim3(64, 32), 256, 0, stream>>>(G, HID1, F, OUT_H1, Wp, bp, OUT);
}

// Round 10
// 1876.398 us; speedup vs baseline: 1.0572x; 1.0313x over previous
//
#include <hip/hip_runtime.h>

typedef unsigned short u16;
typedef unsigned int u32;
typedef unsigned long long u64;
typedef short v8s __attribute__((ext_vector_type(8)));
typedef float v4f __attribute__((ext_vector_type(4)));

#define NN 4096
#define BATCH 32

__device__ __forceinline__ float b2f(u16 u) {
  union { u32 i; float f; } c; c.i = ((u32)u) << 16; return c.f;
}
__device__ __forceinline__ u16 f2b(float f) {
  union { float f; u32 i; } c; c.f = f;
  u32 x = c.i;
  return (u16)((x + 0x7fffu + ((x >> 16) & 1u)) >> 16);
}
__device__ __forceinline__ u32 pk2(float a, float b) {
  return (u32)f2b(a) | ((u32)f2b(b) << 16);
}

typedef const __attribute__((address_space(1))) u32* gp_t;
typedef __attribute__((address_space(3))) u32* lp_t;
__device__ __forceinline__ void gld16(const u16* g, u16* l) {
  __builtin_amdgcn_global_load_lds((gp_t)g, (lp_t)l, 16, 0, 0);
}

#define CBAR() asm volatile("" ::: "memory")
#define BARRIER() do { CBAR(); __builtin_amdgcn_s_barrier(); CBAR(); } while (0)
#define LGKM0() asm volatile("s_waitcnt lgkmcnt(0)" ::: "memory")
#define VMC4() asm volatile("s_waitcnt vmcnt(4)" ::: "memory")
#define VMC3() asm volatile("s_waitcnt vmcnt(3)" ::: "memory")
#define VMC0() asm volatile("s_waitcnt vmcnt(0)" ::: "memory")

// ---------------------------------------------------------------------------
// cvtS: f32 -> bf16 (RNE), 8 elems/thread. grid: 8192 x 256 for 16.8M elems.
// ---------------------------------------------------------------------------
__global__ __launch_bounds__(256) void cvtS(const float* __restrict__ S,
                                            u16* __restrict__ Sb) {
  const u64 idx = ((u64)blockIdx.x * 256 + threadIdx.x) * 8;
  const float4 a = *(const float4*)(S + idx);
  const float4 b = *(const float4*)(S + idx + 4);
  uint4 o;
  o.x = pk2(a.x, a.y); o.y = pk2(a.z, a.w);
  o.z = pk2(b.x, b.y); o.w = pk2(b.z, b.w);
  *(uint4*)(Sb + idx) = o;
}

// ---------------------------------------------------------------------------
// gemm256 (R3/R6 verified, 104.7us): 256x256 tile, BK=64, 8 waves (2Mx4N).
// Minimal-barrier free-run schedule + one-cluster-ahead operand pipelining.
// grid (16, C/256), block 512.
// ---------------------------------------------------------------------------
__global__ __launch_bounds__(512, 2) void gemm256(const u16* __restrict__ A,
                                                  const u16* __restrict__ B,
                                                  u16* __restrict__ Ct,
                                                  const u16* __restrict__ Xt) {
  // 128 KiB: buf b at b*32768 (u16); regions A-h0 0 | A-h1 8192 | B-h0 16384 | B-h1 24576
  __shared__ __align__(16) u16 lds[65536];
  const int t = threadIdx.x;
  const int wave = t >> 6, lane = t & 63;
  const int q = lane >> 4, r16 = lane & 15;
  const int wm = wave >> 2, wn = wave & 3;

  const int nwg = (int)(gridDim.x * gridDim.y);
  const int bid = (int)(blockIdx.y * gridDim.x + blockIdx.x);
  const int swz = (bid & 7) * (nwg >> 3) + (bid >> 3);
  const int m0 = (swz & 15) << 8;   // gridDim.x == 16 always
  const int c0 = (swz >> 4) << 8;

  v4f acc[8][4];
  const v4f vz = {0.f, 0.f, 0.f, 0.f};
#pragma unroll
  for (int i = 0; i < 8; ++i)
#pragma unroll
    for (int j = 0; j < 4; ++j) acc[i][j] = vz;

  const int srow = t >> 3;
  const int sslot = ((t & 7) ^ (srow & 7)) << 3;      // element col offset
  const u16* pA = A + (u64)(m0 + srow) * NN + sslot;
  const u16* pB = B + (u64)(c0 + srow) * NN + sslot;
  const u64 rstep = (u64)64 * NN;
  const u64 hstep = (u64)128 * NN;
  u16* lw = lds + (wave << 9);

  const int sw8 = (q ^ (r16 & 7)) << 3;
  const int aBase = (wm << 13) + (r16 << 6) + sw8;
  const int bBase = 16384 + ((wn >> 1) << 13) + ((wn & 1) << 12) + (r16 << 6) + sw8;

  const int NT = NN >> 6;  // 64 K-tiles

  gld16(pA, lw);
  gld16(pA + rstep, lw + 4096);
  gld16(pA + hstep, lw + 8192);
  gld16(pA + hstep + rstep, lw + 12288);
  gld16(pB, lw + 16384);
  gld16(pB + rstep, lw + 20480);
  gld16(pB + hstep, lw + 24576);
  gld16(pB + hstep + rstep, lw + 28672);
  gld16(pB + 64, lw + 32768 + 16384);
  gld16(pB + 64 + rstep, lw + 32768 + 20480);
  gld16(pB + 64 + hstep, lw + 32768 + 24576);
  gld16(pB + 64 + hstep + rstep, lw + 32768 + 28672);
  VMC4();
  BARRIER();

  v8s af[4][2], bf01[2][2], bf23[2][2];
#pragma unroll
  for (int i = 0; i < 4; ++i) {
    const int a = aBase + (i << 10);
    af[i][0] = *(const v8s*)(lds + a);
    af[i][1] = *(const v8s*)(lds + (a ^ 32));
  }
#pragma unroll
  for (int j = 0; j < 2; ++j) {
    const int b = bBase + (j << 10);
    bf01[j][0] = *(const v8s*)(lds + b);
    bf01[j][1] = *(const v8s*)(lds + (b ^ 32));
  }

#pragma unroll 2
  for (int T = 0; T < NT; ++T) {
    const int bo = (T & 1) << 15;
    const int no = bo ^ 32768;
    const u64 ka = (u64)(T + 1 < NT ? T + 1 : NT - 1) << 6;
    const u64 kb = (u64)(T + 2 < NT ? T + 2 : NT - 1) << 6;

    // ---- phase 0
    gld16(pA + ka, lw + no);
    gld16(pA + ka + rstep, lw + no + 4096);
#pragma unroll
    for (int j = 0; j < 2; ++j) {
      const int b = bo + bBase + ((2 + j) << 10);
      bf23[j][0] = *(const v8s*)(lds + b);
      bf23[j][1] = *(const v8s*)(lds + (b ^ 32));
    }
    __builtin_amdgcn_s_setprio(1);
#pragma unroll
    for (int i = 0; i < 4; ++i)
#pragma unroll
      for (int j = 0; j < 2; ++j) {
        acc[i][j] = __builtin_amdgcn_mfma_f32_16x16x32_bf16(af[i][0], bf01[j][0], acc[i][j], 0, 0, 0);
        acc[i][j] = __builtin_amdgcn_mfma_f32_16x16x32_bf16(af[i][1], bf01[j][1], acc[i][j], 0, 0, 0);
      }
    __builtin_amdgcn_s_setprio(0);

    // ---- phase 1
    gld16(pA + hstep + ka, lw + no + 8192);
    gld16(pA + hstep + ka + rstep, lw + no + 12288);
    LGKM0();
    BARRIER();
    __builtin_amdgcn_s_setprio(1);
#pragma unroll
    for (int i = 0; i < 4; ++i)
#pragma unroll
      for (int j = 0; j < 2; ++j) {
        acc[i][2 + j] = __builtin_amdgcn_mfma_f32_16x16x32_bf16(af[i][0], bf23[j][0], acc[i][2 + j], 0, 0, 0);
        acc[i][2 + j] = __builtin_amdgcn_mfma_f32_16x16x32_bf16(af[i][1], bf23[j][1], acc[i][2 + j], 0, 0, 0);
      }
    __builtin_amdgcn_s_setprio(0);
#pragma unroll
    for (int i = 0; i < 4; ++i) {
      const int a = bo + aBase + ((4 + i) << 10);
      af[i][0] = *(const v8s*)(lds + a);
      af[i][1] = *(const v8s*)(lds + (a ^ 32));
    }
    __builtin_amdgcn_sched_barrier(0);

    // ---- phase 2
    gld16(pB + kb, lw + bo + 16384);
    gld16(pB + kb + rstep, lw + bo + 20480);
    __builtin_amdgcn_s_setprio(1);
#pragma unroll
    for (int i = 0; i < 4; ++i)
#pragma unroll
      for (int j = 0; j < 2; ++j) {
        acc[4 + i][2 + j] = __builtin_amdgcn_mfma_f32_16x16x32_bf16(af[i][0], bf23[j][0], acc[4 + i][2 + j], 0, 0, 0);
        acc[4 + i][2 + j] = __builtin_amdgcn_mfma_f32_16x16x32_bf16(af[i][1], bf23[j][1], acc[4 + i][2 + j], 0, 0, 0);
      }
    __builtin_amdgcn_s_setprio(0);

    // ---- phase 3
    gld16(pB + hstep + kb, lw + bo + 24576);
    gld16(pB + hstep + rstep + kb, lw + bo + 28672);
    VMC4();
    BARRIER();
    __builtin_amdgcn_s_setprio(1);
#pragma unroll
    for (int i = 0; i < 4; ++i)
#pragma unroll
      for (int j = 0; j < 2; ++j) {
        acc[4 + i][j] = __builtin_amdgcn_mfma_f32_16x16x32_bf16(af[i][0], bf01[j][0], acc[4 + i][j], 0, 0, 0);
        acc[4 + i][j] = __builtin_amdgcn_mfma_f32_16x16x32_bf16(af[i][1], bf01[j][1], acc[4 + i][j], 0, 0, 0);
      }
    __builtin_amdgcn_s_setprio(0);
#pragma unroll
    for (int i = 0; i < 4; ++i) {
      const int a = no + aBase + (i << 10);
      af[i][0] = *(const v8s*)(lds + a);
      af[i][1] = *(const v8s*)(lds + (a ^ 32));
    }
#pragma unroll
    for (int j = 0; j < 2; ++j) {
      const int b = no + bBase + (j << 10);
      bf01[j][0] = *(const v8s*)(lds + b);
      bf01[j][1] = *(const v8s*)(lds + (b ^ 32));
    }
    __builtin_amdgcn_sched_barrier(0);
  }

  // ---------------- epilogue ----------------
  VMC0();
  __syncthreads();
#pragma unroll
  for (int i = 0; i < 8; ++i)
#pragma unroll
    for (int j = 0; j < 4; ++j) {
      const int cl = (wn << 6) + (j << 4) + r16;
      const int ml = (wm << 7) + (i << 4) + (q << 2);
      const int phys = (cl << 8) + ((((ml >> 3) ^ (cl & 7)) << 3) | (ml & 7));
      uint2 pv;
      pv.x = pk2(acc[i][j][0], acc[i][j][1]);
      pv.y = pk2(acc[i][j][2], acc[i][j][3]);
      *(uint2*)(lds + phys) = pv;
    }
  __syncthreads();
#pragma unroll
  for (int it = 0; it < 16; ++it) {
    const int f = (it << 9) + t;
    const int cl = f >> 5, sl = f & 31;
    const int phys = (cl << 8) + ((sl ^ (cl & 7)) << 3);
    union { uint4 v; u16 e[8]; } tv;
    tv.v = *(const uint4*)(lds + phys);
    const u64 gi = (u64)(c0 + cl) * NN + m0 + (sl << 3);
    if (Xt) {
      union { uint4 v; u16 e[8]; } xv, ov;
      xv.v = *(const uint4*)(Xt + gi);
#pragma unroll
      for (int s = 0; s < 8; ++s) ov.e[s] = f2b(2.f * b2f(tv.e[s]) - b2f(xv.e[s]));
      *(uint4*)(Ct + gi) = ov.v;
    } else {
      *(uint4*)(Ct + gi) = tv.v;
    }
  }
}

// ---------------------------------------------------------------------------
// gemm144: 256x144 tile for layer-0 (C=2304 -> 16x16 = 256 blocks, exact CU
// fill with 0.5625-size blocks). R6 gemm192 staging/hazard/LDS skeleton
// (A=4 stage-ops, B=3 ops with rows 144..191 padded-never-read, vmcnt(3),
// 2 barriers/tile). Wave mapping 8Mx1N: per-wave 32x144 (acc[2][9]).
// grid (16, 16), block 512.
// ---------------------------------------------------------------------------
__global__ __launch_bounds__(512, 2) void gemm144(const u16* __restrict__ A,
                                                  const u16* __restrict__ B,
                                                  u16* __restrict__ Ct,
                                                  const u16* __restrict__ Xt) {
  // 2 bufs x 28672 u16: A [256][64] at 0 | B [192][64] at 16384
  __shared__ __align__(16) u16 lds[57344];
  const int t = threadIdx.x;
  const int wave = t >> 6, lane = t & 63;
  const int q = lane >> 4, r16 = lane & 15;
  const int wm = wave;                     // 8M x 1N

  const int nwg = (int)(gridDim.x * gridDim.y);   // 256
  const int bid = (int)(blockIdx.y * gridDim.x + blockIdx.x);
  const int swz = (bid & 7) * (nwg >> 3) + (bid >> 3);
  const int m0 = (swz & 15) << 8;                 // gridDim.x == 16
  const int c0 = (swz >> 4) * 144;                // 0..15

  v4f acc[2][9];
  const v4f vz = {0.f, 0.f, 0.f, 0.f};
#pragma unroll
  for (int i = 0; i < 2; ++i)
#pragma unroll
    for (int j = 0; j < 9; ++j) acc[i][j] = vz;

  const int srow = t >> 3;
  const int sslot = ((t & 7) ^ (srow & 7)) << 3;
  const u16* pA = A + (u64)(m0 + srow) * NN + sslot;
  const u16* pB = B + (u64)(c0 + srow) * NN + sslot;  // rows 144..191 slack
  const u64 rstep = (u64)64 * NN;
  u16* lw = lds + (wave << 9);

  const int sw8 = (q ^ (r16 & 7)) << 3;
  const int aBase = (wm << 11) + (r16 << 6) + sw8;        // + i<<10
  const int bBase = 16384 + (r16 << 6) + sw8;             // + j<<10

  const int NT = NN >> 6;  // 64 K-tiles

  // prologue: A(0) 4 ops, B(0) 3 ops, B(1) 3 ops; VMC3 leaves B(1) in flight
  gld16(pA, lw);
  gld16(pA + rstep, lw + 4096);
  gld16(pA + 2 * rstep, lw + 8192);
  gld16(pA + 3 * rstep, lw + 12288);
  gld16(pB, lw + 16384);
  gld16(pB + rstep, lw + 20480);
  gld16(pB + 2 * rstep, lw + 24576);
  gld16(pB + 64, lw + 28672 + 16384);
  gld16(pB + 64 + rstep, lw + 28672 + 20480);
  gld16(pB + 64 + 2 * rstep, lw + 28672 + 24576);
  VMC3();
  BARRIER();

  v8s af[2][2], bfA[5][2], bfB[4][2];
#pragma unroll
  for (int i = 0; i < 2; ++i) {
    const int a = aBase + (i << 10);
    af[i][0] = *(const v8s*)(lds + a);
    af[i][1] = *(const v8s*)(lds + (a ^ 32));
  }
#pragma unroll
  for (int j = 0; j < 5; ++j) {
    const int b = bBase + (j << 10);
    bfA[j][0] = *(const v8s*)(lds + b);
    bfA[j][1] = *(const v8s*)(lds + (b ^ 32));
  }

#pragma unroll 2
  for (int T = 0; T < NT; ++T) {
    const int bo = (T & 1) ? 28672 : 0;
    const int no = bo ^ 28672;
    const u64 ka = (u64)(T + 1 < NT ? T + 1 : NT - 1) << 6;
    const u64 kb = (u64)(T + 2 < NT ? T + 2 : NT - 1) << 6;

    // ---- P0: stage A ops0-1 (T+1) | read bfB | MFMA af x bfA ks0 (10)
    gld16(pA + ka, lw + no);
    gld16(pA + ka + rstep, lw + no + 4096);
#pragma unroll
    for (int j = 0; j < 4; ++j) {
      const int b = bo + bBase + ((5 + j) << 10);
      bfB[j][0] = *(const v8s*)(lds + b);
      bfB[j][1] = *(const v8s*)(lds + (b ^ 32));
    }
    __builtin_amdgcn_s_setprio(1);
#pragma unroll
    for (int i = 0; i < 2; ++i)
#pragma unroll
      for (int j = 0; j < 5; ++j)
        acc[i][j] = __builtin_amdgcn_mfma_f32_16x16x32_bf16(af[i][0], bfA[j][0], acc[i][j], 0, 0, 0);
    __builtin_amdgcn_s_setprio(0);

    // ---- P1: stage A ops2-3 (T+1) | LGKM0 + BARRIER (region WAR) |
    //          MFMA af x bfA ks1 (10)
    gld16(pA + ka + 2 * rstep, lw + no + 8192);
    gld16(pA + ka + 3 * rstep, lw + no + 12288);
    LGKM0();
    BARRIER();
    __builtin_amdgcn_s_setprio(1);
#pragma unroll
    for (int i = 0; i < 2; ++i)
#pragma unroll
      for (int j = 0; j < 5; ++j)
        acc[i][j] = __builtin_amdgcn_mfma_f32_16x16x32_bf16(af[i][1], bfA[j][1], acc[i][j], 0, 0, 0);
    __builtin_amdgcn_s_setprio(0);

    // ---- P2: stage B ops0-1 (T+2) -> bo | MFMA af x bfB ks0 (8)
    gld16(pB + kb, lw + bo + 16384);
    gld16(pB + kb + rstep, lw + bo + 20480);
    __builtin_amdgcn_s_setprio(1);
#pragma unroll
    for (int i = 0; i < 2; ++i)
#pragma unroll
      for (int j = 0; j < 4; ++j)
        acc[i][5 + j] = __builtin_amdgcn_mfma_f32_16x16x32_bf16(af[i][0], bfB[j][0], acc[i][5 + j], 0, 0, 0);
    __builtin_amdgcn_s_setprio(0);

    // ---- P3: stage B op2 (T+2) | MFMA af x bfB ks1 (8) | VMC3 + BARRIER |
    //          prefetch af, bfA from no-buf
    gld16(pB + kb + 2 * rstep, lw + bo + 24576);
    __builtin_amdgcn_s_setprio(1);
#pragma unroll
    for (int i = 0; i < 2; ++i)
#pragma unroll
      for (int j = 0; j < 4; ++j)
        acc[i][5 + j] = __builtin_amdgcn_mfma_f32_16x16x32_bf16(af[i][1], bfB[j][1], acc[i][5 + j], 0, 0, 0);
    __builtin_amdgcn_s_setprio(0);
    VMC3();   // drains A(T+1)+B(T+1); leaves B(T+2)'s 3 ops in flight
    BARRIER();
#pragma unroll
    for (int i = 0; i < 2; ++i) {
      const int a = no + aBase + (i << 10);
      af[i][0] = *(const v8s*)(lds + a);
      af[i][1] = *(const v8s*)(lds + (a ^ 32));
    }
#pragma unroll
    for (int j = 0; j < 5; ++j) {
      const int b = no + bBase + (j << 10);
      bfA[j][0] = *(const v8s*)(lds + b);
      bfA[j][1] = *(const v8s*)(lds + (b ^ 32));
    }
    __builtin_amdgcn_sched_barrier(0);
  }

  // ---------------- epilogue: 144c x 256m through LDS ----------------
  VMC0();
  __syncthreads();
#pragma unroll
  for (int i = 0; i < 2; ++i)
#pragma unroll
    for (int j = 0; j < 9; ++j) {
      const int cl = j * 16 + r16;                           // 0..143
      const int ml = (wm << 5) + (i << 4) + (q << 2);        // 0..252
      const int phys = (cl << 8) + ((((ml >> 3) ^ (cl & 7)) << 3) | (ml & 7));
      uint2 pv;
      pv.x = pk2(acc[i][j][0], acc[i][j][1]);
      pv.y = pk2(acc[i][j][2], acc[i][j][3]);
      *(uint2*)(lds + phys) = pv;
    }
  __syncthreads();
#pragma unroll
  for (int it = 0; it < 9; ++it) {
    const int f = (it << 9) + t;
    const int cl = f >> 5, sl = f & 31;                      // cl 0..143
    const int phys = (cl << 8) + ((sl ^ (cl & 7)) << 3);
    union { uint4 v; u16 e[8]; } tv;
    tv.v = *(const uint4*)(lds + phys);
    const u64 gi = (u64)(c0 + cl) * NN + m0 + (sl << 3);
    if (Xt) {
      union { uint4 v; u16 e[8]; } xv, ov;
      xv.v = *(const uint4*)(Xt + gi);
#pragma unroll
      for (int s = 0; s < 8; ++s) ov.e[s] = f2b(2.f * b2f(tv.e[s]) - b2f(xv.e[s]));
      *(uint4*)(Ct + gi) = ov.v;
    } else {
      *(uint4*)(Ct + gi) = tv.v;
    }
  }
}

// ---------------------------------------------------------------------------
// gemm_s (fallback if workspace too small for bf16 S): A f32, in-loop cvt.
// ---------------------------------------------------------------------------
__global__ __launch_bounds__(256) void gemm_s(const float* __restrict__ A,
                                              const u16* __restrict__ B,
                                              u16* __restrict__ Ct,
                                              const u16* __restrict__ Xt) {
  __shared__ __align__(16) u16 As[4096];
  __shared__ __align__(16) u16 Bs[4096];
  __shared__ __align__(16) u16 T[16384];
  const int t = threadIdx.x;
  const int wave = t >> 6, lane = t & 63;
  const int m0 = blockIdx.x << 7, c0 = blockIdx.y << 7;
  const int wm = (wave >> 1) << 6, wc = (wave & 1) << 6;
  const int q = lane >> 4, r16 = lane & 15;
  v4f acc[4][4];
  const v4f vz = {0.f, 0.f, 0.f, 0.f};
#pragma unroll
  for (int i = 0; i < 4; ++i)
#pragma unroll
    for (int j = 0; j < 4; ++j) acc[i][j] = vz;

  const int sr = t >> 2;
  const int sc = (t & 3) << 3;
  const u64 abase = (u64)(m0 + sr) * NN + sc;
  const u64 bbase = (u64)(c0 + sr) * NN + sc;
  const u64 rstep = (u64)64 * NN;
  u16* as0 = As + sr * 32 + sc;
  u16* as1 = As + (64 + sr) * 32 + sc;
  u16* bs0 = Bs + sr * 32 + sc;
  u16* bs1 = Bs + (64 + sr) * 32 + sc;

  for (int k0 = 0; k0 < NN; k0 += 32) {
    const float4 a0l = *(const float4*)(A + abase + k0);
    const float4 a0h = *(const float4*)(A + abase + k0 + 4);
    const float4 a1l = *(const float4*)(A + abase + rstep + k0);
    const float4 a1h = *(const float4*)(A + abase + rstep + k0 + 4);
    const uint4 b0 = *(const uint4*)(B + bbase + k0);
    const uint4 b1 = *(const uint4*)(B + bbase + rstep + k0);
    uint4 pa0, pa1;
    pa0.x = pk2(a0l.x, a0l.y); pa0.y = pk2(a0l.z, a0l.w);
    pa0.z = pk2(a0h.x, a0h.y); pa0.w = pk2(a0h.z, a0h.w);
    pa1.x = pk2(a1l.x, a1l.y); pa1.y = pk2(a1l.z, a1l.w);
    pa1.z = pk2(a1h.x, a1h.y); pa1.w = pk2(a1h.z, a1h.w);
    __syncthreads();
    *(uint4*)as0 = pa0;
    *(uint4*)as1 = pa1;
    *(uint4*)bs0 = b0;
    *(uint4*)bs1 = b1;
    __syncthreads();
    v8s af[4], bf[4];
#pragma unroll
    for (int i = 0; i < 4; ++i)
      af[i] = *(const v8s*)(As + ((wm + i * 16 + r16) << 5) + (q << 3));
#pragma unroll
    for (int j = 0; j < 4; ++j)
      bf[j] = *(const v8s*)(Bs + ((wc + j * 16 + r16) << 5) + (q << 3));
#pragma unroll
    for (int i = 0; i < 4; ++i)
#pragma unroll
      for (int j = 0; j < 4; ++j)
        acc[i][j] = __builtin_amdgcn_mfma_f32_16x16x32_bf16(af[i], bf[j], acc[i][j], 0, 0, 0);
  }
#pragma unroll
  for (int i = 0; i < 4; ++i)
#pragma unroll
    for (int j = 0; j < 4; ++j) {
      const int cl = wc + j * 16 + r16;
      const int mm = wm + i * 16 + (q << 2);
      uint2 pv;
      pv.x = pk2(acc[i][j][0], acc[i][j][1]);
      pv.y = pk2(acc[i][j][2], acc[i][j][3]);
      *(uint2*)(T + (cl << 7) + mm) = pv;
    }
  __syncthreads();
#pragma unroll
  for (int it = 0; it < 8; ++it) {
    const int flat = it * 256 + t;
    const int cl = flat >> 4;
    const int seg = (flat & 15) << 3;
    const u64 gi = (u64)(c0 + cl) * NN + m0 + seg;
    union { uint4 v; u16 e[8]; } tv;
    tv.v = *(uint4*)(T + (cl << 7) + seg);
    if (Xt) {
      union { uint4 v; u16 e[8]; } xv, ov;
      xv.v = *(const uint4*)(Xt + gi);
#pragma unroll
      for (int s = 0; s < 8; ++s) ov.e[s] = f2b(2.f * b2f(tv.e[s]) - b2f(xv.e[s]));
      *(uint4*)(Ct + gi) = ov.v;
    } else {
      *(uint4*)(Ct + gi) = tv.v;
    }
  }
}

// ---------------------------------------------------------------------------
// Projection: out[b*JSTR + j][n] = act( sum_k Wt[j][k] * F[row(k,b)][n] + b[j] )
// ---------------------------------------------------------------------------
template <int DP, int KTOT>
__global__ __launch_bounds__(256) void proj_k(const u16* __restrict__ Wt,
                                              const u16* __restrict__ F,
                                              const float* __restrict__ bias,
                                              u16* __restrict__ outp,
                                              const int JSTR, const int ACT) {
  __shared__ __align__(16) u16 As2[2048];  // 64 j x 32 k
  __shared__ __align__(16) u16 Bs2[4096];  // 32 k x 128 n
  const int t = threadIdx.x;
  const int wave = t >> 6, lane = t & 63;
  const int q = lane >> 4, r16 = lane & 15;
  const int n0 = blockIdx.x << 7;
  const int j0 = blockIdx.y << 6;
  const int b = blockIdx.z;
  v4f acc[4][2];
  const v4f vz = {0.f, 0.f, 0.f, 0.f};
#pragma unroll
  for (int i = 0; i < 4; ++i) { acc[i][0] = vz; acc[i][1] = vz; }

  const int ar = t >> 2, ac = (t & 3) << 3;
  const u64 wbase = (u64)(j0 + ar) * KTOT + ac;

  for (int k0 = 0; k0 < KTOT; k0 += 32) {
    const uint4 av = *(const uint4*)(Wt + wbase + k0);
    uint4 bv[2];
#pragma unroll
    for (int ci = 0; ci < 2; ++ci) {
      const int c = ci * 256 + t;
      const int kr = c >> 4;
      const int seg = (c & 15) << 3;
      const int kk = k0 + kr;
      const int i = kk / DP;
      const int d = kk - i * DP;
      bv[ci] = *(const uint4*)(F + ((u64)i * (BATCH * DP) + (u64)b * DP + d) * NN + n0 + seg);
    }
    __syncthreads();
    *(uint4*)(As2 + ar * 32 + ac) = av;
#pragma unroll
    for (int ci = 0; ci < 2; ++ci) {
      const int c = ci * 256 + t;
      const int kr = c >> 4;
      const int seg = (c & 15) << 3;
      *(uint4*)(Bs2 + (kr << 7) + seg) = bv[ci];
    }
    __syncthreads();
    v8s af[4], bf[2];
#pragma unroll
    for (int i = 0; i < 4; ++i)
      af[i] = *(const v8s*)(As2 + ((i * 16 + r16) << 5) + (q << 3));
#pragma unroll
    for (int jj = 0; jj < 2; ++jj) {
      const int nn = (wave << 5) + jj * 16 + r16;
      v8s v;
#pragma unroll
      for (int s = 0; s < 8; ++s) v[s] = (short)Bs2[(((q << 3) + s) << 7) + nn];
      bf[jj] = v;
    }
#pragma unroll
    for (int i = 0; i < 4; ++i)
#pragma unroll
      for (int jj = 0; jj < 2; ++jj)
        acc[i][jj] = __builtin_amdgcn_mfma_f32_16x16x32_bf16(af[i], bf[jj], acc[i][jj], 0, 0, 0);
  }
#pragma unroll
  for (int i = 0; i < 4; ++i)
#pragma unroll
    for (int jj = 0; jj < 2; ++jj)
#pragma unroll
      for (int r = 0; r < 4; ++r) {
        const int j = j0 + i * 16 + (q << 2) + r;
        const int n = n0 + (wave << 5) + jj * 16 + r16;
        float v = acc[i][jj][r] + bias[j];
        v = ACT ? (1.f - 2.f / (__expf(2.f * v) + 1.f)) : (1.f / (1.f + __expf(-v)));
        outp[((u64)b * JSTR + j) * NN + n] = f2b(v);
      }
}

// ---------------------------------------------------------------------------
__global__ __launch_bounds__(256) void repackW(const float* __restrict__ W, u16* __restrict__ Wt,
                                               const int D, const int DP, const int KTOT,
                                               const int J) {
  const int idx = blockIdx.x * 256 + threadIdx.x;
  if (idx >= J * KTOT) return;
  const int j = idx / KTOT, k = idx - j * KTOT;
  const int i = k / DP, d = k - i * DP;
  u16 v = 0;
  if (i < 5 && d < D) v = f2b(W[(i * D + d) * J + j]);
  Wt[idx] = v;
}

// ---------------------------------------------------------------------------
__global__ __launch_bounds__(256) void pack0(const float* __restrict__ x,
                                             const float* __restrict__ hid0,
                                             u16* __restrict__ F0) {
  __shared__ __align__(16) u16 Hs[64 * 72];
  const int b = blockIdx.y, n0 = blockIdx.x << 6, t = threadIdx.x;
  const int r = t >> 2, ds = t & 3;
  const float* hrow = hid0 + ((u64)b * NN + n0 + r) * 64;
#pragma unroll
  for (int c4 = 0; c4 < 4; ++c4) {
    const float4 v = *(const float4*)(hrow + ds * 16 + c4 * 4);
    uint2 p;
    p.x = pk2(v.x, v.y);
    p.y = pk2(v.z, v.w);
    *(uint2*)(Hs + r * 72 + ds * 16 + c4 * 4) = p;
  }
  __syncthreads();
#pragma unroll
  for (int c2 = 0; c2 < 2; ++c2) {
    union { uint4 v; u16 h[8]; } o;
#pragma unroll
    for (int s = 0; s < 8; ++s) o.h[s] = Hs[(ds * 16 + c2 * 8 + s) * 72 + r];
    *(uint4*)(F0 + ((u64)b * 72 + 1 + r) * NN + n0 + ds * 16 + c2 * 8) = o.v;
  }
  if (t < 64) {
    F0[(u64)b * 72 * NN + n0 + t] = f2b(x[(u64)b * NN + n0 + t]);
  } else if (t < 120) {
    const int tt = t - 64;
    const int row = 65 + (tt >> 3), seg = (tt & 7) << 3;
    uint4 z; z.x = z.y = z.z = z.w = 0;
    *(uint4*)(F0 + ((u64)b * 72 + row) * NN + n0 + seg) = z;
  }
}

// ---------------------------------------------------------------------------
__global__ __launch_bounds__(256) void pack1(const float* __restrict__ hid1,
                                             u16* __restrict__ F1) {
  __shared__ __align__(16) u16 Hs[64 * 72];
  const int b = blockIdx.y, n0 = blockIdx.x << 6, t = threadIdx.x;
  const int r = t >> 2, ds = t & 3;
  const float* hrow = hid1 + ((u64)b * NN + n0 + r) * 64;
#pragma unroll
  for (int c4 = 0; c4 < 4; ++c4) {
    const float4 v = *(const float4*)(hrow + ds * 16 + c4 * 4);
    uint2 p;
    p.x = pk2(v.x, v.y);
    p.y = pk2(v.z, v.w);
    *(uint2*)(Hs + r * 72 + ds * 16 + c4 * 4) = p;
  }
  __syncthreads();
#pragma unroll
  for (int c2 = 0; c2 < 2; ++c2) {
    union { uint4 v; u16 h[8]; } o;
#pragma unroll
    for (int s = 0; s < 8; ++s) o.h[s] = Hs[(ds * 16 + c2 * 8 + s) * 72 + r];
    *(uint4*)(F1 + ((u64)b * 128 + 64 + r) * NN + n0 + ds * 16 + c2 * 8) = o.v;
  }
}

// ---------------------------------------------------------------------------
__global__ __launch_bounds__(256) void candpack(const u16* __restrict__ G, u16* __restrict__ F,
                                                const int DP, const int OFF) {
  const int u = blockIdx.x * 256 + threadIdx.x;
  const int b = u >> 15;
  const int d = (u >> 9) & 63;
  const int seg = (u & 511) << 3;
  union { uint4 v; u16 h[8]; } g, f, o;
  g.v = *(const uint4*)(G + ((u64)b * 128 + d) * NN + seg);
  u16* fp = F + ((u64)b * DP + OFF + d) * NN + seg;
  f.v = *(const uint4*)fp;
#pragma unroll
  for (int s = 0; s < 8; ++s) o.h[s] = f2b(b2f(f.h[s]) * b2f(g.h[s]));
  *(uint4*)fp = o.v;
}

// ---------------------------------------------------------------------------
// hnew_k: h' = u*h + (1-u)*c ; writes HnF (bf16 rows) and outH (f32 [b][n][64]).
// If outPred != null (layer 1): also fused predict — outPred[b*NN+n] =
// sum_d h'[n][d]*Wp[d] + bp  (T2 holds full d-range per block).
// ---------------------------------------------------------------------------
__global__ __launch_bounds__(256) void hnew_k(const u16* __restrict__ G,
                                              const float* __restrict__ hidL,
                                              u16* __restrict__ HnF,
                                              float* __restrict__ outH,
                                              const float* __restrict__ Wp,
                                              const float* __restrict__ bp,
                                              float* __restrict__ outPred) {
  __shared__ __align__(16) float Hs[64 * 72];
  __shared__ __align__(16) float T2[64 * 72];
  __shared__ float wsh[64];
  __shared__ float bbs;
  const int b = blockIdx.y, n0 = blockIdx.x << 6, t = threadIdx.x;
  const int r = t >> 2, ds = t & 3;
  const float* hrow = hidL + ((u64)b * NN + n0 + r) * 64;
  if (outPred) {
    if (t < 64) wsh[t] = Wp[t];
    if (t == 64) bbs = bp[0];
  }
#pragma unroll
  for (int c4 = 0; c4 < 4; ++c4)
    *(float4*)(Hs + r * 72 + ds * 16 + c4 * 4) = *(const float4*)(hrow + ds * 16 + c4 * 4);
  __syncthreads();
#pragma unroll
  for (int c2 = 0; c2 < 2; ++c2) {
    const int ncol = ds * 16 + c2 * 8;
    union { uint4 v; u16 h[8]; } uv, cv, o;
    uv.v = *(const uint4*)(G + ((u64)b * 128 + 64 + r) * NN + n0 + ncol);
    cv.v = *(const uint4*)(G + ((u64)b * 128 + r) * NN + n0 + ncol);
#pragma unroll
    for (int s = 0; s < 8; ++s) {
      const int nl = ncol + s;
      const float uu = b2f(uv.h[s]);
      const float hh = Hs[nl * 72 + r];
      const float cc = b2f(cv.h[s]);
      const float v = uu * hh + (1.f - uu) * cc;
      o.h[s] = f2b(v);
      T2[nl * 72 + r] = v;
    }
    *(uint4*)(HnF + ((u64)b * 128 + r) * NN + n0 + ncol) = o.v;
  }
  __syncthreads();
  const int nl2 = t >> 2, dseg = (t & 3) << 4;
#pragma unroll
  for (int c4 = 0; c4 < 4; ++c4) {
    const float4 v = *(const float4*)(T2 + nl2 * 72 + dseg + c4 * 4);
    *(float4*)(outH + ((u64)b * NN + n0 + nl2) * 64 + dseg + c4 * 4) = v;
  }
  if (outPred && t < 64) {
    float s = bbs;
#pragma unroll
    for (int rr = 0; rr < 64; ++rr) s += T2[t * 72 + rr] * wsh[rr];
    outPred[(u64)b * NN + n0 + t] = s;
  }
}

extern "C" void kernel_launch(void* const* d_in, const int* in_sizes, int n_in,
                              void* d_out, int out_size, void* d_ws, size_t ws_size,
                              hipStream_t stream) {
  const float* X   = (const float*)d_in[0];
  const float* HID = (const float*)d_in[1];
  const float* Sf  = (const float*)d_in[2];
  const float* Sb  = (const float*)d_in[3];
  const float* Wg0 = (const float*)d_in[4];
  const float* bg0 = (const float*)d_in[5];
  const float* Wc0 = (const float*)d_in[6];
  const float* bc0 = (const float*)d_in[7];
  const float* Wg1 = (const float*)d_in[8];
  const float* bg1 = (const float*)d_in[9];
  const float* Wc1 = (const float*)d_in[10];
  const float* bc1 = (const float*)d_in[11];
  const float* Wp  = (const float*)d_in[12];
  const float* bp  = (const float*)d_in[13];
  float* OUT = (float*)d_out;
  char* ws = (char*)d_ws;

  u16* F = (u16*)(ws);
  u16* G = (u16*)(ws + 167772160ull);
  const u64 NEED_BIG = 167772160ull + 33554432ull + 2ull * 33554432ull + 393216ull;
  const bool big = ws_size >= NEED_BIG;
  u16* Sfb = (u16*)(ws + 167772160ull + 33554432ull);
  u16* Sbb = Sfb + (u64)NN * NN;
  u16* WT = big ? (Sbb + (u64)NN * NN)
                : (u16*)(ws + 167772160ull + 33554432ull);
  u16* Wg0t = WT;                   // 128 x 384
  u16* Wc0t = Wg0t + 128 * 384;     // 64 x 384
  u16* Wg1t = Wc0t + 64 * 384;      // 128 x 640
  u16* Wc1t = Wg1t + 128 * 640;     // 64 x 640

  const float* HID1 = HID + (u64)32 * 4096 * 64;
  float* OUT_H0 = OUT + 131072;
  float* OUT_H1 = OUT + 131072 + 8388608;

  // zero the layer-0 K-padding region of F (rows 11520..13823), read by proj i=5
  hipMemsetAsync(ws + (u64)11520 * NN * 2, 0, (u64)2304 * NN * 2, stream);

  if (big) {
    cvtS<<<8192, 256, 0, stream>>>(Sf, Sfb);
    cvtS<<<8192, 256, 0, stream>>>(Sb, Sbb);
  }

  repackW<<<(128 * 384 + 255) / 256, 256, 0, stream>>>(Wg0, Wg0t, 65, 72, 384, 128);
  repackW<<<(64 * 384 + 255) / 256, 256, 0, stream>>>(Wc0, Wc0t, 65, 72, 384, 64);
  repackW<<<(128 * 640 + 255) / 256, 256, 0, stream>>>(Wg1, Wg1t, 128, 128, 640, 128);
  repackW<<<(64 * 640 + 255) / 256, 256, 0, stream>>>(Wc1, Wc1t, 128, 128, 640, 64);

  // ---------------- layer 0 (Dp=72, C=2304) ----------------
  pack0<<<dim3(64, 32), 256, 0, stream>>>(X, HID, F);
  const u64 R0 = (u64)2304 * NN;
  const dim3 g144(16, 16);
  if (big) {
    gemm144<<<g144, 512, 0, stream>>>(Sfb, F, F + R0, nullptr);
    gemm144<<<g144, 512, 0, stream>>>(Sbb, F, F + 3 * R0, nullptr);
    gemm144<<<g144, 512, 0, stream>>>(Sfb, F + R0, F + 2 * R0, F);
    gemm144<<<g144, 512, 0, stream>>>(Sbb, F + 3 * R0, F + 4 * R0, F);
  } else {
    gemm_s<<<dim3(32, 18), 256, 0, stream>>>(Sf, F, F + R0, nullptr);
    gemm_s<<<dim3(32, 18), 256, 0, stream>>>(Sb, F, F + 3 * R0, nullptr);
    gemm_s<<<dim3(32, 18), 256, 0, stream>>>(Sf, F + R0, F + 2 * R0, F);
    gemm_s<<<dim3(32, 18), 256, 0, stream>>>(Sb, F + 3 * R0, F + 4 * R0, F);
  }
  proj_k<72, 384><<<dim3(32, 2, 32), 256, 0, stream>>>(Wg0t, F, bg0, G, 128, 0);
  candpack<<<4096, 256, 0, stream>>>(G, F, 72, 1);
  if (big) {
    gemm144<<<g144, 512, 0, stream>>>(Sfb, F, F + R0, nullptr);
    gemm144<<<g144, 512, 0, stream>>>(Sbb, F, F + 3 * R0, nullptr);
    gemm144<<<g144, 512, 0, stream>>>(Sfb, F + R0, F + 2 * R0, F);
    gemm144<<<g144, 512, 0, stream>>>(Sbb, F + 3 * R0, F + 4 * R0, F);
  } else {
    gemm_s<<<dim3(32, 18), 256, 0, stream>>>(Sf, F, F + R0, nullptr);
    gemm_s<<<dim3(32, 18), 256, 0, stream>>>(Sb, F, F + 3 * R0, nullptr);
    gemm_s<<<dim3(32, 18), 256, 0, stream>>>(Sf, F + R0, F + 2 * R0, F);
    gemm_s<<<dim3(32, 18), 256, 0, stream>>>(Sb, F + 3 * R0, F + 4 * R0, F);
  }
  proj_k<72, 384><<<dim3(32, 1, 32), 256, 0, stream>>>(Wc0t, F, bc0, G, 128, 1);
  hnew_k<<<dim3(64, 32), 256, 0, stream>>>(G, HID, F, OUT_H0, nullptr, nullptr, nullptr);

  // ---------------- layer 1 (Dp=128, C=4096) ----------------
  pack1<<<dim3(64, 32), 256, 0, stream>>>(HID1, F);
  const u64 R1 = (u64)4096 * NN;
  const dim3 g256(16, 16);
  if (big) {
    gemm256<<<g256, 512, 0, stream>>>(Sfb, F, F + R1, nullptr);
    gemm256<<<g256, 512, 0, stream>>>(Sbb, F, F + 3 * R1, nullptr);
    gemm256<<<g256, 512, 0, stream>>>(Sfb, F + R1, F + 2 * R1, F);
    gemm256<<<g256, 512, 0, stream>>>(Sbb, F + 3 * R1, F + 4 * R1, F);
  } else {
    gemm_s<<<dim3(32, 32), 256, 0, stream>>>(Sf, F, F + R1, nullptr);
    gemm_s<<<dim3(32, 32), 256, 0, stream>>>(Sb, F, F + 3 * R1, nullptr);
    gemm_s<<<dim3(32, 32), 256, 0, stream>>>(Sf, F + R1, F + 2 * R1, F);
    gemm_s<<<dim3(32, 32), 256, 0, stream>>>(Sb, F + 3 * R1, F + 4 * R1, F);
  }
  proj_k<128, 640><<<dim3(32, 2, 32), 256, 0, stream>>>(Wg1t, F, bg1, G, 128, 0);
  candpack<<<4096, 256, 0, stream>>>(G, F, 128, 64);
  if (big) {
    gemm256<<<g256, 512, 0, stream>>>(Sfb, F, F + R1, nullptr);
    gemm256<<<g256, 512, 0, stream>>>(Sbb, F, F + 3 * R1, nullptr);
    gemm256<<<g256, 512, 0, stream>>>(Sfb, F + R1, F + 2 * R1, F);
    gemm256<<<g256, 512, 0, stream>>>(Sbb, F + 3 * R1, F + 4 * R1, F);
  } else {
    gemm_s<<<dim3(32, 32), 256, 0, stream>>>(Sf, F, F + R1, nullptr);
    gemm_s<<<dim3(32, 32), 256, 0, stream>>>(Sb, F, F + 3 * R1, nullptr);
    gemm_s<<<dim3(32, 32), 256, 0, stream>>>(Sf, F + R1, F + 2 * R1, F);
    gemm_s<<<dim3(32, 32), 256, 0, stream>>>(Sb, F + 3 * R1, F + 4 * R1, F);
  }
  proj_k<128, 640><<<dim3(32, 1, 32), 256, 0, stream>>>(Wc1t, F, bc1, G, 128, 1);
  hnew_k<<<dim3(64, 32), 256, 0, stream>>>(G, HID1, F, OUT_H1, Wp, bp, OUT);
}